// Round 17
// baseline (881.948 us; speedup 1.0000x reference)
//
#include <hip/hip_runtime.h>
#include <math.h>

typedef __attribute__((ext_vector_type(8))) short bf16x8;   // 8 bf16 (4 VGPRs)
typedef __attribute__((ext_vector_type(4))) float f32x4;

// ---------------- workspace layout (bytes) ----------------
constexpr size_t XW_OFF  = 0;                                   // 96 MB (gemm out; dead after 2nd gru)
constexpr size_t O1_OFF  = XW_OFF + 65536ull * 384 * 4;         // 32 MB
constexpr size_t O2_OFF  = O1_OFF + 512ull * 128 * 128 * 4;     // 32 MB (also A-bf16 staging pre-gru2)
constexpr size_t Y0_OFF  = O2_OFF + 512ull * 128 * 128 * 4;     // 128 KB
constexpr size_t Y1_OFF  = Y0_OFF + 256ull * 128 * 4;           // 128 KB
constexpr size_t MMD_OFF = Y1_OFF + 256ull * 128 * 4;           // 1 KB
constexpr size_t WTS_OFF = MMD_OFF + 256 * 4;                   // 1 KB
constexpr size_t BW_OFF  = WTS_OFF + 256 * 4;                   // 1 KB
constexpr size_t WBF_OFF = BW_OFF + 4096;                       // 8 bf16 weight slots = 786 KB
// aliases into dead regions:
constexpr size_t NRM_OFF = XW_OFF;                              // norms (after gru2)
constexpr size_t CHI_OFF = XW_OFF + (1ull << 20);               // mmd bf16 hi
constexpr size_t CLO_OFF = CHI_OFF + 36ull * 1024 * 1024;       // mmd bf16 lo
constexpr size_t ABH_OFF = O2_OFF;                              // gemm A bf16 hi (16 MB)
constexpr size_t ABL_OFF = O2_OFF + 16ull * 1024 * 1024;        // gemm A bf16 lo (16 MB)

static __device__ __forceinline__ unsigned short f2bf(float x) {
    unsigned u = __float_as_uint(x);
    unsigned r = (u + 0x7FFFu + ((u >> 16) & 1u)) >> 16;
    return (unsigned short)r;
}
static __device__ __forceinline__ float bf2f(unsigned short b) {
    return __uint_as_float((unsigned)b << 16);
}

// ---------------- K0a: W f32 -> bf16 hi/lo (384x128, also used for whh) ----------------
__global__ __launch_bounds__(256) void cvt_w(const float* __restrict__ W,
                                             unsigned short* __restrict__ whi,
                                             unsigned short* __restrict__ wlo)
{
    int f = blockIdx.x * 256 + threadIdx.x;    // float4 index, 12288 total
    if (f >= 12288) return;
    float4 v = ((const float4*)W)[f];
    ushort4 uh, ul;
    uh.x = f2bf(v.x); ul.x = f2bf(v.x - bf2f(uh.x));
    uh.y = f2bf(v.y); ul.y = f2bf(v.y - bf2f(uh.y));
    uh.z = f2bf(v.z); ul.z = f2bf(v.z - bf2f(uh.z));
    uh.w = f2bf(v.w); ul.w = f2bf(v.w - bf2f(uh.w));
    *(ushort4*)(whi + 4 * f) = uh;
    *(ushort4*)(wlo + 4 * f) = ul;
}

// ---------------- K0b: A f32 [M][128] -> bf16 hi/lo (row-major) ----------------
__global__ __launch_bounds__(256) void cvt_a(const float* __restrict__ A,
                                             unsigned short* __restrict__ ahi,
                                             unsigned short* __restrict__ alo)
{
    const int t = threadIdx.x;
#pragma unroll
    for (int it = 0; it < 4; ++it) {
        size_t f = (size_t)blockIdx.x * 1024 + it * 256 + t;   // float4 idx
        float4 v = ((const float4*)A)[f];
        ushort4 uh, ul;
        uh.x = f2bf(v.x); ul.x = f2bf(v.x - bf2f(uh.x));
        uh.y = f2bf(v.y); ul.y = f2bf(v.y - bf2f(uh.y));
        uh.z = f2bf(v.z); ul.z = f2bf(v.z - bf2f(uh.z));
        uh.w = f2bf(v.w); ul.w = f2bf(v.w - bf2f(uh.w));
        *(ushort4*)(ahi + 4 * f) = uh;
        *(ushort4*)(alo + 4 * f) = ul;
    }
}

// ---------------- K1/K3: C[M][384] = A[M][128] @ W[384][128]^T + bias (MFMA) ----------------
__global__ __launch_bounds__(256) void gemm_mfma(const unsigned short* __restrict__ ahi,
                                                 const unsigned short* __restrict__ alo,
                                                 const unsigned short* __restrict__ whi,
                                                 const unsigned short* __restrict__ wlo,
                                                 const float* __restrict__ bias,
                                                 float* __restrict__ C)
{
    const int m0 = blockIdx.x * 128;
    const int n0 = blockIdx.y * 128;          // 0,128,256 (N=384)
    const int tid  = threadIdx.x;
    const int lane = tid & 63;
    const int wave = tid >> 6;
    const int wm = wave >> 1, wn = wave & 1;
    const int r16 = lane & 15;
    const int kq  = lane >> 4;

    const int arow = m0 + wm * 64 + r16;
    const int brow = n0 + wn * 64 + r16;

    f32x4 acc[4][4];
#pragma unroll
    for (int mf = 0; mf < 4; ++mf)
#pragma unroll
        for (int nf = 0; nf < 4; ++nf) acc[mf][nf] = (f32x4){0.f, 0.f, 0.f, 0.f};

#pragma unroll 1
    for (int kc = 0; kc < 128; kc += 32) {
        const int koff = kc + 8 * kq;
        bf16x8 ah[4], al[4], bh[4], bl[4];
#pragma unroll
        for (int mf = 0; mf < 4; ++mf) {
            size_t off = (size_t)(arow + mf * 16) * 128 + koff;
            ah[mf] = *(const bf16x8*)(ahi + off);
            al[mf] = *(const bf16x8*)(alo + off);
        }
#pragma unroll
        for (int nf = 0; nf < 4; ++nf) {
            size_t off = (size_t)(brow + nf * 16) * 128 + koff;
            bh[nf] = *(const bf16x8*)(whi + off);
            bl[nf] = *(const bf16x8*)(wlo + off);
        }
#pragma unroll
        for (int mf = 0; mf < 4; ++mf)
#pragma unroll
            for (int nf = 0; nf < 4; ++nf) {
                acc[mf][nf] = __builtin_amdgcn_mfma_f32_16x16x32_bf16(ah[mf], bh[nf], acc[mf][nf], 0, 0, 0);
                acc[mf][nf] = __builtin_amdgcn_mfma_f32_16x16x32_bf16(ah[mf], bl[nf], acc[mf][nf], 0, 0, 0);
                acc[mf][nf] = __builtin_amdgcn_mfma_f32_16x16x32_bf16(al[mf], bh[nf], acc[mf][nf], 0, 0, 0);
            }
    }

    float nb[4];
#pragma unroll
    for (int nf = 0; nf < 4; ++nf) nb[nf] = bias[n0 + wn * 64 + nf * 16 + r16];

#pragma unroll
    for (int mf = 0; mf < 4; ++mf)
#pragma unroll
        for (int nf = 0; nf < 4; ++nf)
#pragma unroll
            for (int r = 0; r < 4; ++r) {
                int row = m0 + wm * 64 + mf * 16 + kq * 4 + r;
                int col = n0 + wn * 64 + nf * 16 + r16;
                C[(size_t)row * 384 + col] = acc[mf][nf][r] + nb[nf];
            }
}

// ---------------- K2/K4: GRU scan via MFMA, raw-barrier (no vmcnt drain) ----------------
// R16 post-mortem: ALL five gru structures ~190-273us share one thing: a
// __syncthreads() per step, and the compiler emits s_waitcnt vmcnt(0) before
// s_barrier -> the x-prefetch loads and out stores are DRAINED every step
// (~900cy HBM latency exposed, per step, no matter how deep the prefetch).
// Fix (T4 counted-vmcnt core): raw s_barrier preceded by lgkmcnt(0) only --
// LDS h-exchange made visible, VMEM stays in flight across the barrier;
// compiler's automatic vmcnt wait before x USE is now 2 steps after issue.
__global__ __launch_bounds__(512, 1) void gru_mfma(const float* __restrict__ xw,
                                                   const unsigned short* __restrict__ whi,
                                                   const unsigned short* __restrict__ wlo,
                                                   const float* __restrict__ bhh,
                                                   float* __restrict__ out)
{
    const int blk  = blockIdx.x;            // 0..31
    const int tid  = threadIdx.x;
    const int w    = tid >> 6;              // 0..7
    const int lane = tid & 63;
    const int b    = lane & 15;             // batch row within block
    const int kq   = lane >> 4;             // 0..3
    const int u0   = 16 * w + 4 * kq;       // unit slice base (4 units)
    const int B    = blk * 16 + b;          // global batch row

    // A-frags (whh) hi/lo: [gate][kchunk], resident all 128 steps
    bf16x8 Ah[3][4], Al[3][4];
#pragma unroll
    for (int g = 0; g < 3; ++g)
#pragma unroll
        for (int c = 0; c < 4; ++c) {
            size_t off = (size_t)(128 * g + 16 * w + b) * 128 + 32 * c + 8 * kq;
            Ah[g][c] = *(const bf16x8*)(whi + off);
            Al[g][c] = *(const bf16x8*)(wlo + off);
        }

    f32x4 bh[3];
#pragma unroll
    for (int g = 0; g < 3; ++g) bh[g] = *(const f32x4*)(bhh + 128 * g + u0);

    __shared__ __align__(16) unsigned short hb[2][2][2048];   // [dbuf][hi/lo][16*128]

    const int wslot = (b * 128 + u0) ^ ((b & 7) << 3);
    *(ushort4*)&hb[0][0][wslot] = (ushort4){0, 0, 0, 0};
    *(ushort4*)&hb[0][1][wslot] = (ushort4){0, 0, 0, 0};
    __syncthreads();

    f32x4 hold = (f32x4){0.f, 0.f, 0.f, 0.f};
    const float* xb = xw + (size_t)B * 128 * 384;

    // two named x sets: A = even steps, B = odd steps
    f32x4 xAr = *(const f32x4*)(xb + u0);
    f32x4 xAz = *(const f32x4*)(xb + 128 + u0);
    f32x4 xAn = *(const f32x4*)(xb + 256 + u0);
    f32x4 xBr = *(const f32x4*)(xb + 384 + u0);
    f32x4 xBz = *(const f32x4*)(xb + 384 + 128 + u0);
    f32x4 xBn = *(const f32x4*)(xb + 384 + 256 + u0);

#define GRU_BODY(STCUR, CUR, XR, XZ, XN)                                              \
    {                                                                                 \
        bf16x8 Bh[4], Bl[4];                                                          \
        _Pragma("unroll")                                                             \
        for (int c = 0; c < 4; ++c) {                                                 \
            int rslot = (b * 128 + 32 * c + 8 * kq) ^ ((b & 7) << 3);                 \
            Bh[c] = *(const bf16x8*)&hb[CUR][0][rslot];                               \
            Bl[c] = *(const bf16x8*)&hb[CUR][1][rslot];                               \
        }                                                                             \
        f32x4 acc[3];                                                                 \
        _Pragma("unroll")                                                             \
        for (int g = 0; g < 3; ++g) acc[g] = (f32x4){0.f, 0.f, 0.f, 0.f};             \
        _Pragma("unroll")                                                             \
        for (int c = 0; c < 4; ++c)                                                   \
            _Pragma("unroll")                                                         \
            for (int g = 0; g < 3; ++g)                                               \
                acc[g] = __builtin_amdgcn_mfma_f32_16x16x32_bf16(Ah[g][c], Bh[c], acc[g], 0, 0, 0); \
        _Pragma("unroll")                                                             \
        for (int c = 0; c < 4; ++c)                                                   \
            _Pragma("unroll")                                                         \
            for (int g = 0; g < 3; ++g)                                               \
                acc[g] = __builtin_amdgcn_mfma_f32_16x16x32_bf16(Ah[g][c], Bl[c], acc[g], 0, 0, 0); \
        _Pragma("unroll")                                                             \
        for (int c = 0; c < 4; ++c)                                                   \
            _Pragma("unroll")                                                         \
            for (int g = 0; g < 3; ++g)                                               \
                acc[g] = __builtin_amdgcn_mfma_f32_16x16x32_bf16(Al[g][c], Bh[c], acc[g], 0, 0, 0); \
        f32x4 hnew;                                                                   \
        ushort4 nhi, nlo;                                                             \
        _Pragma("unroll")                                                             \
        for (int r = 0; r < 4; ++r) {                                                 \
            float rr = 1.f / (1.f + __expf(-(XR[r] + acc[0][r] + bh[0][r])));         \
            float zz = 1.f / (1.f + __expf(-(XZ[r] + acc[1][r] + bh[1][r])));         \
            float xa = XN[r] + rr * (acc[2][r] + bh[2][r]);                           \
            float ex = __expf(-2.f * fabsf(xa));                                      \
            float th = (1.f - ex) / (1.f + ex);                                       \
            th = copysignf(th, xa);                                                   \
            hnew[r] = (1.f - zz) * th + zz * hold[r];                                 \
        }                                                                             \
        hold = hnew;                                                                  \
        nhi.x = f2bf(hnew[0]); nlo.x = f2bf(hnew[0] - bf2f(nhi.x));                   \
        nhi.y = f2bf(hnew[1]); nlo.y = f2bf(hnew[1] - bf2f(nhi.y));                   \
        nhi.z = f2bf(hnew[2]); nlo.z = f2bf(hnew[2] - bf2f(nhi.z));                   \
        nhi.w = f2bf(hnew[3]); nlo.w = f2bf(hnew[3] - bf2f(nhi.w));                   \
        *(ushort4*)&hb[(CUR) ^ 1][0][wslot] = nhi;                                    \
        *(ushort4*)&hb[(CUR) ^ 1][1][wslot] = nlo;                                    \
        *(f32x4*)(out + ((size_t)B * 128 + (STCUR)) * 128 + u0) = hnew;               \
        /* re-issue this set for step STCUR+2 (consumed 2 steps from now) */          \
        {                                                                             \
            const int ld = ((STCUR) + 2 < 128) ? (STCUR) + 2 : 127;                   \
            XR = *(const f32x4*)(xb + ld * 384 + u0);                                 \
            XZ = *(const f32x4*)(xb + ld * 384 + 128 + u0);                           \
            XN = *(const f32x4*)(xb + ld * 384 + 256 + u0);                           \
        }                                                                             \
        /* raw barrier: drain LDS only, leave VMEM (x loads, out stores) in flight */ \
        asm volatile("s_waitcnt lgkmcnt(0)" ::: "memory");                            \
        __builtin_amdgcn_s_barrier();                                                 \
    }

#pragma unroll 1
    for (int st = 0; st < 128; st += 2) {
        GRU_BODY(st,     0, xAr, xAz, xAn)
        GRU_BODY(st + 1, 1, xBr, xBz, xBn)
    }
#undef GRU_BODY
}

// ---------------- K5: y[256][128] += xall @ gw^T (split-K, atomic) ----------------
__global__ __launch_bounds__(256) void gate_gemm(const float* __restrict__ o,
                                                 const float* __restrict__ gw,
                                                 float* __restrict__ y)
{
    __shared__ __align__(16) float As[64][36];
    __shared__ __align__(16) float Ws[64][36];
    const int tid = threadIdx.x;
    const int tx = tid & 15, ty = tid >> 4;
    const int m0 = blockIdx.x * 64, n0 = blockIdx.y * 64;
    const int k0beg = blockIdx.z * 1024;

    float acc[4][4];
#pragma unroll
    for (int i = 0; i < 4; ++i)
#pragma unroll
        for (int j = 0; j < 4; ++j) acc[i][j] = 0.f;

#pragma unroll 1
    for (int kc = k0beg; kc < k0beg + 1024; kc += 32) {
#pragma unroll
        for (int it = 0; it < 2; ++it) {
            int idx = tid + it * 256;
            int row = idx >> 3;
            int c4  = (idx & 7) * 4;
            int kap = kc + c4;
            int s = kap >> 8, half = (kap >> 7) & 1, h = kap & 127;
            float4 va = *(const float4*)(o + ((size_t)(m0 + row + 256 * half) * 128 + s) * 128 + h);
            *(float4*)&As[row][c4] = va;
            float4 vw = *(const float4*)(gw + (size_t)(n0 + row) * 32768 + kap);
            *(float4*)&Ws[row][c4] = vw;
        }
        __syncthreads();
#pragma unroll 1
        for (int k0 = 0; k0 < 32; k0 += 4) {
            float4 a4[4], w4[4];
#pragma unroll
            for (int i = 0; i < 4; ++i) a4[i] = *(float4*)&As[ty + 16 * i][k0];
#pragma unroll
            for (int j = 0; j < 4; ++j) w4[j] = *(float4*)&Ws[tx + 16 * j][k0];
#pragma unroll
            for (int i = 0; i < 4; ++i)
#pragma unroll
                for (int j = 0; j < 4; ++j) {
                    acc[i][j] += a4[i].x * w4[j].x + a4[i].y * w4[j].y +
                                 a4[i].z * w4[j].z + a4[i].w * w4[j].w;
                }
        }
        __syncthreads();
    }
#pragma unroll
    for (int i = 0; i < 4; ++i)
#pragma unroll
        for (int j = 0; j < 4; ++j) {
            int r = m0 + ty + 16 * i, c = n0 + tx + 16 * j;
            atomicAdd(&y[r * 128 + c], acc[i][j]);
        }
}

// ---------------- K6: BN + sigmoid-mean + softmax -> weights (128) ----------------
__global__ void gate_reduce(const float* __restrict__ y,
                            const float* __restrict__ gamma,
                            const float* __restrict__ beta,
                            float* __restrict__ wts_ws,
                            float* __restrict__ wts_out)
{
    const int o = threadIdx.x;   // 128 threads
    float sum = 0.f, sumsq = 0.f;
    for (int b = 0; b < 256; ++b) {
        float v = y[b * 128 + o];
        sum += v; sumsq += v * v;
    }
    float m = sum * (1.f / 256.f);
    float var = sumsq * (1.f / 256.f) - m * m;
    float inv = rsqrtf(var + 1e-5f);
    float g = gamma[o], be = beta[o];
    float sw = 0.f;
    for (int b = 0; b < 256; ++b) {
        float v = y[b * 128 + o];
        float t = g * (v - m) * inv + be;
        sw += 1.f / (1.f + __expf(-t));
    }
    float wo = sw * (1.f / 256.f);

    __shared__ float red[128];
    red[o] = wo;
    __syncthreads();
    for (int st = 64; st > 0; st >>= 1) {
        if (o < st) red[o] = fmaxf(red[o], red[o + st]);
        __syncthreads();
    }
    float mx = red[0];
    __syncthreads();
    float e = __expf(wo - mx);
    red[o] = e;
    __syncthreads();
    for (int st = 64; st > 0; st >>= 1) {
        if (o < st) red[o] += red[o + st];
        __syncthreads();
    }
    float r = e / red[0];
    wts_ws[o] = r;
    wts_out[o] = r;
}

// ---------------- K7: fc_out = o2[:, -1, :] @ fc_w^T + fc_b ----------------
__global__ void fc_kern(const float* __restrict__ o2,
                        const float* __restrict__ fw,
                        const float* __restrict__ fb,
                        float* __restrict__ out)
{
    int gid = blockIdx.x * blockDim.x + threadIdx.x;
    if (gid >= 3072) return;
    int b = gid / 6, oo = gid - b * 6;
    const float* xr = o2 + ((size_t)b * 128 + 127) * 128;
    const float* wr = fw + oo * 128;
    float acc = fb[oo];
#pragma unroll 16
    for (int k = 0; k < 128; ++k) acc += xr[k] * wr[k];
    out[gid] = acc;
}

// ---------------- K8a: per-row norms (f32, exact) ----------------
__global__ __launch_bounds__(512) void row_norms(const float* __restrict__ o1,
                                                 const float* __restrict__ o2,
                                                 float* __restrict__ norms)
{
    const int s = blockIdx.x;          // 128
    const int l = blockIdx.y;          // 2
    const float* o = l ? o2 : o1;
    const int i = threadIdx.x;         // 512 rows
    const float* r = o + ((size_t)i * 128 + s) * 128;
    float acc = 0.f;
#pragma unroll
    for (int k = 0; k < 128; k += 4) {
        float4 v = *(const float4*)(r + k);
        acc += v.x * v.x + v.y * v.y + v.z * v.z + v.w * v.w;
    }
    norms[((size_t)l * 128 + s) * 512 + i] = acc;
}

// ---------------- K8b: bf16 hi/lo conversion, pair-major layout (for mmd) ----------------
__global__ __launch_bounds__(512) void cvt_bf16(const float* __restrict__ o1,
                                                const float* __restrict__ o2,
                                                unsigned short* __restrict__ chi,
                                                unsigned short* __restrict__ clo)
{
    const int s = blockIdx.x;          // 128
    const int l = blockIdx.y;          // 2
    const float* o = l ? o2 : o1;
    const int t = threadIdx.x;         // 512
    const int h4 = (t & 31) * 4;
    const size_t pb = ((size_t)l * 128 + s) * 512 * 128;
#pragma unroll 1
    for (int i = t >> 5; i < 512; i += 16) {
        float4 v = *(const float4*)(o + ((size_t)i * 128 + s) * 128 + h4);
        ushort4 uh, ul;
        uh.x = f2bf(v.x); ul.x = f2bf(v.x - bf2f(uh.x));
        uh.y = f2bf(v.y); ul.y = f2bf(v.y - bf2f(uh.y));
        uh.z = f2bf(v.z); ul.z = f2bf(v.z - bf2f(uh.z));
        uh.w = f2bf(v.w); ul.w = f2bf(v.w - bf2f(uh.w));
        *(ushort4*)(chi + pb + (size_t)i * 128 + h4) = uh;
        *(ushort4*)(clo + pb + (size_t)i * 128 + h4) = ul;
    }
}

// ---------------- K8c: per-pair bandwidth ----------------
__global__ void pair_stats(const float* __restrict__ o1,
                           const float* __restrict__ o2,
                           float* __restrict__ bw)
{
    const int p = blockIdx.x;          // 256 pairs
    const int l = p >> 7, s = p & 127;
    const float* o = l ? o2 : o1;
    const int tid = threadIdx.x;       // 256
    const int h = tid & 127, half = tid >> 7;

    float acc_u = 0.f, acc_sq = 0.f;
    for (int r = 0; r < 256; ++r) {
        int i = half * 256 + r;
        float v = o[((size_t)i * 128 + s) * 128 + h];
        acc_u += v; acc_sq += v * v;
    }
    __shared__ float u2[256];
    __shared__ float red[256];
    u2[tid] = acc_u;
    red[tid] = acc_sq;
    __syncthreads();
    for (int st = 128; st > 0; st >>= 1) {
        if (tid < st) red[tid] += red[tid + st];
        __syncthreads();
    }
    float S1 = red[0];
    __syncthreads();
    float uu = 0.f;
    if (tid < 128) { float t = u2[tid] + u2[tid + 128]; uu = t * t; }
    red[tid] = uu;
    __syncthreads();
    for (int st = 128; st > 0; st >>= 1) {
        if (tid < st) red[tid] += red[tid + st];
        __syncthreads();
    }
    if (tid == 0) {
        float S2 = red[0];
        float d2s = 1024.f * S1 - 2.f * S2;
        bw[p] = d2s / (512.f * 512.f - 512.f) * 0.25f;
    }
}

// ---------------- K9: MMD via bf16 hi/lo MFMA Gram ----------------
__global__ __launch_bounds__(256) void mmd_kern(const unsigned short* __restrict__ chi,
                                                const unsigned short* __restrict__ clo,
                                                const float* __restrict__ norms,
                                                const float* __restrict__ bw,
                                                float* __restrict__ mmdv)
{
    const int lin = blockIdx.x;               // 0..2559
    const int v   = (lin & 7) * 320 + (lin >> 3);
    const int p   = v / 10;                   // pair
    const int tp  = v - p * 10;               // tile-pair
    int ti, tj;
    if (tp < 4)      { ti = 0; tj = tp; }
    else if (tp < 7) { ti = 1; tj = tp - 3; }
    else if (tp < 9) { ti = 2; tj = tp - 5; }
    else             { ti = 3; tj = 3; }
    const float sgn  = ((ti < 2) == (tj < 2)) ? 1.f : -1.f;
    const float coef = sgn * ((ti == tj) ? 1.f : 2.f);

    const int tid  = threadIdx.x;
    const int lane = tid & 63;
    const int wave = tid >> 6;                // 0..3
    const int wm = wave >> 1, wn = wave & 1;
    const int r16 = lane & 15;
    const int kq  = lane >> 4;                // 0..3

    const size_t pbase = (size_t)p * 512 * 128;
    const int arow = ti * 128 + wm * 64 + r16;
    const int brow = tj * 128 + wn * 64 + r16;

    f32x4 acc[4][4];
#pragma unroll
    for (int mf = 0; mf < 4; ++mf)
#pragma unroll
        for (int nf = 0; nf < 4; ++nf) acc[mf][nf] = (f32x4){0.f, 0.f, 0.f, 0.f};

#pragma unroll 1
    for (int kc = 0; kc < 128; kc += 32) {
        const size_t koff = (size_t)kc + 8 * kq;
        bf16x8 ah[4], al[4], bh[4], bl[4];
#pragma unroll
        for (int mf = 0; mf < 4; ++mf) {
            size_t off = pbase + (size_t)(arow + mf * 16) * 128 + koff;
            ah[mf] = *(const bf16x8*)(chi + off);
            al[mf] = *(const bf16x8*)(clo + off);
        }
#pragma unroll
        for (int nf = 0; nf < 4; ++nf) {
            size_t off = pbase + (size_t)(brow + nf * 16) * 128 + koff;
            bh[nf] = *(const bf16x8*)(chi + off);
            bl[nf] = *(const bf16x8*)(clo + off);
        }
#pragma unroll
        for (int mf = 0; mf < 4; ++mf)
#pragma unroll
            for (int nf = 0; nf < 4; ++nf) {
                acc[mf][nf] = __builtin_amdgcn_mfma_f32_16x16x32_bf16(ah[mf], bh[nf], acc[mf][nf], 0, 0, 0);
                acc[mf][nf] = __builtin_amdgcn_mfma_f32_16x16x32_bf16(ah[mf], bl[nf], acc[mf][nf], 0, 0, 0);
                acc[mf][nf] = __builtin_amdgcn_mfma_f32_16x16x32_bf16(al[mf], bh[nf], acc[mf][nf], 0, 0, 0);
            }
    }

    const float* np_ = norms + (size_t)p * 512;
    float na[4][4], nb[4];
#pragma unroll
    for (int mf = 0; mf < 4; ++mf)
#pragma unroll
        for (int r = 0; r < 4; ++r)
            na[mf][r] = np_[ti * 128 + wm * 64 + mf * 16 + (lane >> 4) * 4 + r];
#pragma unroll
    for (int nf = 0; nf < 4; ++nf)
        nb[nf] = np_[tj * 128 + wn * 64 + nf * 16 + (lane & 15)];

    const float bwv = bw[p];
    const float c4 = -1.f / (bwv * 16.f);
    float tot = 0.f;
#pragma unroll
    for (int mf = 0; mf < 4; ++mf)
#pragma unroll
        for (int nf = 0; nf < 4; ++nf)
#pragma unroll
            for (int r = 0; r < 4; ++r) {
                float d2 = na[mf][r] + nb[nf] - 2.f * acc[mf][nf][r];
                float e4 = __expf(c4 * d2);
                float e3 = e4 * e4;
                float e2 = e3 * e3;
                float e1 = e2 * e2;
                float e0 = e1 * e1;
                tot += ((e0 + e1) + (e2 + e3)) + e4;
            }
    tot *= coef;

    __shared__ float rbuf[4];
    for (int off = 32; off > 0; off >>= 1) tot += __shfl_down(tot, off);
    if ((tid & 63) == 0) rbuf[tid >> 6] = tot;
    __syncthreads();
    if (tid == 0) atomicAdd(&mmdv[p], rbuf[0] + rbuf[1] + rbuf[2] + rbuf[3]);
}

// ---------------- K10: loss = sum(wts * mmd) / 65536 ----------------
__global__ void final_loss(const float* __restrict__ wts,
                           const float* __restrict__ mmdv,
                           float* __restrict__ out)
{
    const int t = threadIdx.x;  // 256
    float v = wts[t] * mmdv[t];
    __shared__ float red[256];
    red[t] = v;
    __syncthreads();
    for (int st = 128; st > 0; st >>= 1) {
        if (t < st) red[t] += red[t + st];
        __syncthreads();
    }
    if (t == 0) out[0] = red[0] * (1.f / 65536.f);
}

// ---------------- launch ----------------
extern "C" void kernel_launch(void* const* d_in, const int* in_sizes, int n_in,
                              void* d_out, int out_size, void* d_ws, size_t ws_size,
                              hipStream_t stream)
{
    (void)in_sizes; (void)n_in; (void)out_size; (void)ws_size;
    const float* x    = (const float*)d_in[0];
    const float* wih0 = (const float*)d_in[1];
    const float* whh0 = (const float*)d_in[2];
    const float* bih0 = (const float*)d_in[3];
    const float* bhh0 = (const float*)d_in[4];
    const float* wih1 = (const float*)d_in[5];
    const float* whh1 = (const float*)d_in[6];
    const float* bih1 = (const float*)d_in[7];
    const float* bhh1 = (const float*)d_in[8];
    const float* gw0  = (const float*)d_in[9];
    const float* bg0  = (const float*)d_in[11];
    const float* bb0  = (const float*)d_in[12];
    const float* gw1  = (const float*)d_in[13];
    const float* bg1  = (const float*)d_in[15];
    const float* bb1  = (const float*)d_in[16];
    const float* fcw  = (const float*)d_in[17];
    const float* fcb  = (const float*)d_in[18];

    float* out = (float*)d_out;
    char*  ws  = (char*)d_ws;
    float* xw   = (float*)(ws + XW_OFF);
    float* o1   = (float*)(ws + O1_OFF);
    float* o2   = (float*)(ws + O2_OFF);
    float* y0   = (float*)(ws + Y0_OFF);
    float* y1   = (float*)(ws + Y1_OFF);
    float* mmdv = (float*)(ws + MMD_OFF);
    float* wts  = (float*)(ws + WTS_OFF);
    float* bwv  = (float*)(ws + BW_OFF);
    float* nrm  = (float*)(ws + NRM_OFF);
    unsigned short* chi  = (unsigned short*)(ws + CHI_OFF);
    unsigned short* clo  = (unsigned short*)(ws + CLO_OFF);
    unsigned short* abh  = (unsigned short*)(ws + ABH_OFF);   // aliases o2 (pre-gru2)
    unsigned short* abl  = (unsigned short*)(ws + ABL_OFF);
    unsigned short* whi0 = (unsigned short*)(ws + WBF_OFF);
    unsigned short* wlo0 = whi0 + 49152;
    unsigned short* whi1 = wlo0 + 49152;
    unsigned short* wlo1 = whi1 + 49152;
    unsigned short* hhi0 = wlo1 + 49152;
    unsigned short* hlo0 = hhi0 + 49152;
    unsigned short* hhi1 = hlo0 + 49152;
    unsigned short* hlo1 = hhi1 + 49152;

    hipMemsetAsync(y0, 0, (256 * 128 * 2 + 256) * sizeof(float), stream);

    cvt_w<<<48, 256, 0, stream>>>(wih0, whi0, wlo0);
    cvt_w<<<48, 256, 0, stream>>>(wih1, whi1, wlo1);
    cvt_w<<<48, 256, 0, stream>>>(whh0, hhi0, hlo0);
    cvt_w<<<48, 256, 0, stream>>>(whh1, hhi1, hlo1);

    cvt_a<<<2048, 256, 0, stream>>>(x, abh, abl);
    gemm_mfma<<<dim3(512, 3), 256, 0, stream>>>(abh, abl, whi0, wlo0, bih0, xw);
    gru_mfma<<<32, 512, 0, stream>>>(xw, hhi0, hlo0, bhh0, o1);

    cvt_a<<<2048, 256, 0, stream>>>(o1, abh, abl);
    gemm_mfma<<<dim3(512, 3), 256, 0, stream>>>(abh, abl, whi1, wlo1, bih1, xw);
    gru_mfma<<<32, 512, 0, stream>>>(xw, hhi1, hlo1, bhh1, o2);   // overwrites abh/abl (safe)

    gate_gemm<<<dim3(4, 2, 32), 256, 0, stream>>>(o1, gw0, y0);
    gate_gemm<<<dim3(4, 2, 32), 256, 0, stream>>>(o2, gw1, y1);
    gate_reduce<<<1, 128, 0, stream>>>(y0, bg0, bb0, wts, out + 3073);
    gate_reduce<<<1, 128, 0, stream>>>(y1, bg1, bb1, wts + 128, out + 3073 + 128);

    fc_kern<<<12, 256, 0, stream>>>(o2, fcw, fcb, out);

    row_norms<<<dim3(128, 2), 512, 0, stream>>>(o1, o2, nrm);      // xw dead from here
    cvt_bf16<<<dim3(128, 2), 512, 0, stream>>>(o1, o2, chi, clo);
    pair_stats<<<256, 256, 0, stream>>>(o1, o2, bwv);
    mmd_kern<<<2560, 256, 0, stream>>>(chi, clo, nrm, bwv, mmdv);
    final_loss<<<1, 256, 0, stream>>>(wts, mmdv, out + 3072);
}

// Round 18
// 853.109 us; speedup vs baseline: 1.0338x; 1.0338x over previous
//
#include <hip/hip_runtime.h>
#include <math.h>

typedef __attribute__((ext_vector_type(8))) short bf16x8;   // 8 bf16 (4 VGPRs)
typedef __attribute__((ext_vector_type(4))) float f32x4;

// ---------------- workspace layout (bytes) ----------------
constexpr size_t XW_OFF  = 0;                                   // 96 MB (gemm out; dead after 2nd gru)
constexpr size_t O1_OFF  = XW_OFF + 65536ull * 384 * 4;         // 32 MB
constexpr size_t O2_OFF  = O1_OFF + 512ull * 128 * 128 * 4;     // 32 MB (also A-bf16 staging pre-gru2)
constexpr size_t Y0_OFF  = O2_OFF + 512ull * 128 * 128 * 4;     // 128 KB
constexpr size_t Y1_OFF  = Y0_OFF + 256ull * 128 * 4;           // 128 KB
constexpr size_t MMD_OFF = Y1_OFF + 256ull * 128 * 4;           // 1 KB
constexpr size_t WTS_OFF = MMD_OFF + 256 * 4;                   // 1 KB
constexpr size_t BW_OFF  = WTS_OFF + 256 * 4;                   // 1 KB
constexpr size_t WBF_OFF = BW_OFF + 4096;                       // 8 bf16 weight slots = 786 KB
// aliases into dead regions:
constexpr size_t NRM_OFF = XW_OFF;                              // norms (after gru2)
constexpr size_t CHI_OFF = XW_OFF + (1ull << 20);               // mmd bf16 hi
constexpr size_t CLO_OFF = CHI_OFF + 36ull * 1024 * 1024;       // mmd bf16 lo
constexpr size_t ABH_OFF = O2_OFF;                              // gemm A bf16 hi (16 MB)
constexpr size_t ABL_OFF = O2_OFF + 16ull * 1024 * 1024;        // gemm A bf16 lo (16 MB)

static __device__ __forceinline__ unsigned short f2bf(float x) {
    unsigned u = __float_as_uint(x);
    unsigned r = (u + 0x7FFFu + ((u >> 16) & 1u)) >> 16;
    return (unsigned short)r;
}
static __device__ __forceinline__ float bf2f(unsigned short b) {
    return __uint_as_float((unsigned)b << 16);
}

// ---------------- K0a: 4x W f32 -> bf16 hi/lo in ONE launch ----------------
__global__ __launch_bounds__(256) void cvt_w4(const float* __restrict__ W0, const float* __restrict__ W1,
                                              const float* __restrict__ W2, const float* __restrict__ W3,
                                              unsigned short* __restrict__ H0, unsigned short* __restrict__ L0,
                                              unsigned short* __restrict__ H1, unsigned short* __restrict__ L1,
                                              unsigned short* __restrict__ H2, unsigned short* __restrict__ L2,
                                              unsigned short* __restrict__ H3, unsigned short* __restrict__ L3)
{
    const int which = blockIdx.y;
    const float* W = (which == 0) ? W0 : (which == 1) ? W1 : (which == 2) ? W2 : W3;
    unsigned short* whi = (which == 0) ? H0 : (which == 1) ? H1 : (which == 2) ? H2 : H3;
    unsigned short* wlo = (which == 0) ? L0 : (which == 1) ? L1 : (which == 2) ? L2 : L3;
    int f = blockIdx.x * 256 + threadIdx.x;    // float4 index, 12288 total
    if (f >= 12288) return;
    float4 v = ((const float4*)W)[f];
    ushort4 uh, ul;
    uh.x = f2bf(v.x); ul.x = f2bf(v.x - bf2f(uh.x));
    uh.y = f2bf(v.y); ul.y = f2bf(v.y - bf2f(uh.y));
    uh.z = f2bf(v.z); ul.z = f2bf(v.z - bf2f(uh.z));
    uh.w = f2bf(v.w); ul.w = f2bf(v.w - bf2f(uh.w));
    *(ushort4*)(whi + 4 * f) = uh;
    *(ushort4*)(wlo + 4 * f) = ul;
}

// ---------------- K0b: A f32 [M][128] -> bf16 hi/lo (only needed for x) ----------------
__global__ __launch_bounds__(256) void cvt_a(const float* __restrict__ A,
                                             unsigned short* __restrict__ ahi,
                                             unsigned short* __restrict__ alo)
{
    const int t = threadIdx.x;
#pragma unroll
    for (int it = 0; it < 4; ++it) {
        size_t f = (size_t)blockIdx.x * 1024 + it * 256 + t;   // float4 idx
        float4 v = ((const float4*)A)[f];
        ushort4 uh, ul;
        uh.x = f2bf(v.x); ul.x = f2bf(v.x - bf2f(uh.x));
        uh.y = f2bf(v.y); ul.y = f2bf(v.y - bf2f(uh.y));
        uh.z = f2bf(v.z); ul.z = f2bf(v.z - bf2f(uh.z));
        uh.w = f2bf(v.w); ul.w = f2bf(v.w - bf2f(uh.w));
        *(ushort4*)(ahi + 4 * f) = uh;
        *(ushort4*)(alo + 4 * f) = ul;
    }
}

// ---------------- K1/K3: C[M][384] = A[M][128] @ W[384][128]^T + bias (MFMA) ----------------
__global__ __launch_bounds__(256) void gemm_mfma(const unsigned short* __restrict__ ahi,
                                                 const unsigned short* __restrict__ alo,
                                                 const unsigned short* __restrict__ whi,
                                                 const unsigned short* __restrict__ wlo,
                                                 const float* __restrict__ bias,
                                                 float* __restrict__ C)
{
    const int m0 = blockIdx.x * 128;
    const int n0 = blockIdx.y * 128;          // 0,128,256 (N=384)
    const int tid  = threadIdx.x;
    const int lane = tid & 63;
    const int wave = tid >> 6;
    const int wm = wave >> 1, wn = wave & 1;
    const int r16 = lane & 15;
    const int kq  = lane >> 4;

    const int arow = m0 + wm * 64 + r16;
    const int brow = n0 + wn * 64 + r16;

    f32x4 acc[4][4];
#pragma unroll
    for (int mf = 0; mf < 4; ++mf)
#pragma unroll
        for (int nf = 0; nf < 4; ++nf) acc[mf][nf] = (f32x4){0.f, 0.f, 0.f, 0.f};

#pragma unroll 1
    for (int kc = 0; kc < 128; kc += 32) {
        const int koff = kc + 8 * kq;
        bf16x8 ah[4], al[4], bh[4], bl[4];
#pragma unroll
        for (int mf = 0; mf < 4; ++mf) {
            size_t off = (size_t)(arow + mf * 16) * 128 + koff;
            ah[mf] = *(const bf16x8*)(ahi + off);
            al[mf] = *(const bf16x8*)(alo + off);
        }
#pragma unroll
        for (int nf = 0; nf < 4; ++nf) {
            size_t off = (size_t)(brow + nf * 16) * 128 + koff;
            bh[nf] = *(const bf16x8*)(whi + off);
            bl[nf] = *(const bf16x8*)(wlo + off);
        }
#pragma unroll
        for (int mf = 0; mf < 4; ++mf)
#pragma unroll
            for (int nf = 0; nf < 4; ++nf) {
                acc[mf][nf] = __builtin_amdgcn_mfma_f32_16x16x32_bf16(ah[mf], bh[nf], acc[mf][nf], 0, 0, 0);
                acc[mf][nf] = __builtin_amdgcn_mfma_f32_16x16x32_bf16(ah[mf], bl[nf], acc[mf][nf], 0, 0, 0);
                acc[mf][nf] = __builtin_amdgcn_mfma_f32_16x16x32_bf16(al[mf], bh[nf], acc[mf][nf], 0, 0, 0);
            }
    }

    float nb[4];
#pragma unroll
    for (int nf = 0; nf < 4; ++nf) nb[nf] = bias[n0 + wn * 64 + nf * 16 + r16];

#pragma unroll
    for (int mf = 0; mf < 4; ++mf)
#pragma unroll
        for (int nf = 0; nf < 4; ++nf)
#pragma unroll
            for (int r = 0; r < 4; ++r) {
                int row = m0 + wm * 64 + mf * 16 + kq * 4 + r;
                int col = n0 + wn * 64 + nf * 16 + r16;
                C[(size_t)row * 384 + col] = acc[mf][nf][r] + nb[nf];
            }
}

// ---------------- K2/K4: GRU scan via MFMA (R16 structure, plateau accepted) ----------------
// Six structural variants all land 190-273us -> structural plateau; stop.
// New: when abh/abl non-null, store nhi/nlo (bf16 hi/lo of hnew, already
// computed for the h-exchange) directly in gemm-A layout -> deletes cvt_a#2.
__global__ __launch_bounds__(512, 1) void gru_mfma(const float* __restrict__ xw,
                                                   const unsigned short* __restrict__ whi,
                                                   const unsigned short* __restrict__ wlo,
                                                   const float* __restrict__ bhh,
                                                   float* __restrict__ out,
                                                   unsigned short* __restrict__ abh,
                                                   unsigned short* __restrict__ abl)
{
    const int blk  = blockIdx.x;            // 0..31
    const int tid  = threadIdx.x;
    const int w    = tid >> 6;              // 0..7
    const int lane = tid & 63;
    const int b    = lane & 15;             // batch row within block
    const int kq   = lane >> 4;             // 0..3
    const int u0   = 16 * w + 4 * kq;       // unit slice base (4 units)
    const int B    = blk * 16 + b;          // global batch row

    bf16x8 Ah[3][4], Al[3][4];
#pragma unroll
    for (int g = 0; g < 3; ++g)
#pragma unroll
        for (int c = 0; c < 4; ++c) {
            size_t off = (size_t)(128 * g + 16 * w + b) * 128 + 32 * c + 8 * kq;
            Ah[g][c] = *(const bf16x8*)(whi + off);
            Al[g][c] = *(const bf16x8*)(wlo + off);
        }

    f32x4 bh[3];
#pragma unroll
    for (int g = 0; g < 3; ++g) bh[g] = *(const f32x4*)(bhh + 128 * g + u0);

    __shared__ __align__(16) unsigned short hb[2][2][2048];   // [dbuf][hi/lo][16*128]

    const int wslot = (b * 128 + u0) ^ ((b & 7) << 3);
    *(ushort4*)&hb[0][0][wslot] = (ushort4){0, 0, 0, 0};
    *(ushort4*)&hb[0][1][wslot] = (ushort4){0, 0, 0, 0};
    __syncthreads();

    f32x4 hold = (f32x4){0.f, 0.f, 0.f, 0.f};
    const float* xb = xw + (size_t)B * 128 * 384;

    f32x4 xAr = *(const f32x4*)(xb + u0);
    f32x4 xAz = *(const f32x4*)(xb + 128 + u0);
    f32x4 xAn = *(const f32x4*)(xb + 256 + u0);
    f32x4 xBr = *(const f32x4*)(xb + 384 + u0);
    f32x4 xBz = *(const f32x4*)(xb + 384 + 128 + u0);
    f32x4 xBn = *(const f32x4*)(xb + 384 + 256 + u0);

#define GRU_BODY(STCUR, CUR, XR, XZ, XN)                                              \
    {                                                                                 \
        bf16x8 Bh[4], Bl[4];                                                          \
        _Pragma("unroll")                                                             \
        for (int c = 0; c < 4; ++c) {                                                 \
            int rslot = (b * 128 + 32 * c + 8 * kq) ^ ((b & 7) << 3);                 \
            Bh[c] = *(const bf16x8*)&hb[CUR][0][rslot];                               \
            Bl[c] = *(const bf16x8*)&hb[CUR][1][rslot];                               \
        }                                                                             \
        f32x4 acc[3];                                                                 \
        _Pragma("unroll")                                                             \
        for (int g = 0; g < 3; ++g) acc[g] = (f32x4){0.f, 0.f, 0.f, 0.f};             \
        _Pragma("unroll")                                                             \
        for (int c = 0; c < 4; ++c)                                                   \
            _Pragma("unroll")                                                         \
            for (int g = 0; g < 3; ++g)                                               \
                acc[g] = __builtin_amdgcn_mfma_f32_16x16x32_bf16(Ah[g][c], Bh[c], acc[g], 0, 0, 0); \
        _Pragma("unroll")                                                             \
        for (int c = 0; c < 4; ++c)                                                   \
            _Pragma("unroll")                                                         \
            for (int g = 0; g < 3; ++g)                                               \
                acc[g] = __builtin_amdgcn_mfma_f32_16x16x32_bf16(Ah[g][c], Bl[c], acc[g], 0, 0, 0); \
        _Pragma("unroll")                                                             \
        for (int c = 0; c < 4; ++c)                                                   \
            _Pragma("unroll")                                                         \
            for (int g = 0; g < 3; ++g)                                               \
                acc[g] = __builtin_amdgcn_mfma_f32_16x16x32_bf16(Al[g][c], Bh[c], acc[g], 0, 0, 0); \
        f32x4 hnew;                                                                   \
        ushort4 nhi, nlo;                                                             \
        _Pragma("unroll")                                                             \
        for (int r = 0; r < 4; ++r) {                                                 \
            float rr = 1.f / (1.f + __expf(-(XR[r] + acc[0][r] + bh[0][r])));         \
            float zz = 1.f / (1.f + __expf(-(XZ[r] + acc[1][r] + bh[1][r])));         \
            float xa = XN[r] + rr * (acc[2][r] + bh[2][r]);                           \
            float ex = __expf(-2.f * fabsf(xa));                                      \
            float th = (1.f - ex) / (1.f + ex);                                       \
            th = copysignf(th, xa);                                                   \
            hnew[r] = (1.f - zz) * th + zz * hold[r];                                 \
        }                                                                             \
        hold = hnew;                                                                  \
        nhi.x = f2bf(hnew[0]); nlo.x = f2bf(hnew[0] - bf2f(nhi.x));                   \
        nhi.y = f2bf(hnew[1]); nlo.y = f2bf(hnew[1] - bf2f(nhi.y));                   \
        nhi.z = f2bf(hnew[2]); nlo.z = f2bf(hnew[2] - bf2f(nhi.z));                   \
        nhi.w = f2bf(hnew[3]); nlo.w = f2bf(hnew[3] - bf2f(nhi.w));                   \
        *(ushort4*)&hb[(CUR) ^ 1][0][wslot] = nhi;                                    \
        *(ushort4*)&hb[(CUR) ^ 1][1][wslot] = nlo;                                    \
        *(f32x4*)(out + ((size_t)B * 128 + (STCUR)) * 128 + u0) = hnew;               \
        if (abh) {                                                                    \
            *(ushort4*)(abh + ((size_t)B * 128 + (STCUR)) * 128 + u0) = nhi;          \
            *(ushort4*)(abl + ((size_t)B * 128 + (STCUR)) * 128 + u0) = nlo;          \
        }                                                                             \
        {                                                                             \
            const int ld = ((STCUR) + 2 < 128) ? (STCUR) + 2 : 127;                   \
            XR = *(const f32x4*)(xb + ld * 384 + u0);                                 \
            XZ = *(const f32x4*)(xb + ld * 384 + 128 + u0);                           \
            XN = *(const f32x4*)(xb + ld * 384 + 256 + u0);                           \
        }                                                                             \
        asm volatile("s_waitcnt lgkmcnt(0)" ::: "memory");                            \
        __builtin_amdgcn_s_barrier();                                                 \
    }

#pragma unroll 1
    for (int st = 0; st < 128; st += 2) {
        GRU_BODY(st,     0, xAr, xAz, xAn)
        GRU_BODY(st + 1, 1, xBr, xBz, xBn)
    }
#undef GRU_BODY
}

// ---------------- K5: y[256][128] += xall @ gw^T (split-K, atomic) ----------------
__global__ __launch_bounds__(256) void gate_gemm(const float* __restrict__ o,
                                                 const float* __restrict__ gw,
                                                 float* __restrict__ y)
{
    __shared__ __align__(16) float As[64][36];
    __shared__ __align__(16) float Ws[64][36];
    const int tid = threadIdx.x;
    const int tx = tid & 15, ty = tid >> 4;
    const int m0 = blockIdx.x * 64, n0 = blockIdx.y * 64;
    const int k0beg = blockIdx.z * 1024;

    float acc[4][4];
#pragma unroll
    for (int i = 0; i < 4; ++i)
#pragma unroll
        for (int j = 0; j < 4; ++j) acc[i][j] = 0.f;

#pragma unroll 1
    for (int kc = k0beg; kc < k0beg + 1024; kc += 32) {
#pragma unroll
        for (int it = 0; it < 2; ++it) {
            int idx = tid + it * 256;
            int row = idx >> 3;
            int c4  = (idx & 7) * 4;
            int kap = kc + c4;
            int s = kap >> 8, half = (kap >> 7) & 1, h = kap & 127;
            float4 va = *(const float4*)(o + ((size_t)(m0 + row + 256 * half) * 128 + s) * 128 + h);
            *(float4*)&As[row][c4] = va;
            float4 vw = *(const float4*)(gw + (size_t)(n0 + row) * 32768 + kap);
            *(float4*)&Ws[row][c4] = vw;
        }
        __syncthreads();
#pragma unroll 1
        for (int k0 = 0; k0 < 32; k0 += 4) {
            float4 a4[4], w4[4];
#pragma unroll
            for (int i = 0; i < 4; ++i) a4[i] = *(float4*)&As[ty + 16 * i][k0];
#pragma unroll
            for (int j = 0; j < 4; ++j) w4[j] = *(float4*)&Ws[tx + 16 * j][k0];
#pragma unroll
            for (int i = 0; i < 4; ++i)
#pragma unroll
                for (int j = 0; j < 4; ++j) {
                    acc[i][j] += a4[i].x * w4[j].x + a4[i].y * w4[j].y +
                                 a4[i].z * w4[j].z + a4[i].w * w4[j].w;
                }
        }
        __syncthreads();
    }
#pragma unroll
    for (int i = 0; i < 4; ++i)
#pragma unroll
        for (int j = 0; j < 4; ++j) {
            int r = m0 + ty + 16 * i, c = n0 + tx + 16 * j;
            atomicAdd(&y[r * 128 + c], acc[i][j]);
        }
}

// ---------------- K6: BN + sigmoid-mean + softmax, both layers in ONE launch ----------------
__global__ void gate_reduce2(const float* __restrict__ y0, const float* __restrict__ y1,
                             const float* __restrict__ g0, const float* __restrict__ b0,
                             const float* __restrict__ g1, const float* __restrict__ b1,
                             float* __restrict__ wts_ws, float* __restrict__ wts_out)
{
    const int which = blockIdx.x;
    const float* y     = which ? y1 : y0;
    const float* gamma = which ? g1 : g0;
    const float* beta  = which ? b1 : b0;
    float* ws_p  = wts_ws + which * 128;
    float* out_p = wts_out + which * 128;

    const int o = threadIdx.x;   // 128 threads
    float sum = 0.f, sumsq = 0.f;
    for (int b = 0; b < 256; ++b) {
        float v = y[b * 128 + o];
        sum += v; sumsq += v * v;
    }
    float m = sum * (1.f / 256.f);
    float var = sumsq * (1.f / 256.f) - m * m;
    float inv = rsqrtf(var + 1e-5f);
    float g = gamma[o], be = beta[o];
    float sw = 0.f;
    for (int b = 0; b < 256; ++b) {
        float v = y[b * 128 + o];
        float t = g * (v - m) * inv + be;
        sw += 1.f / (1.f + __expf(-t));
    }
    float wo = sw * (1.f / 256.f);

    __shared__ float red[128];
    red[o] = wo;
    __syncthreads();
    for (int st = 64; st > 0; st >>= 1) {
        if (o < st) red[o] = fmaxf(red[o], red[o + st]);
        __syncthreads();
    }
    float mx = red[0];
    __syncthreads();
    float e = __expf(wo - mx);
    red[o] = e;
    __syncthreads();
    for (int st = 64; st > 0; st >>= 1) {
        if (o < st) red[o] += red[o + st];
        __syncthreads();
    }
    float r = e / red[0];
    ws_p[o] = r;
    out_p[o] = r;
}

// ---------------- K7: fc_out = o2[:, -1, :] @ fc_w^T + fc_b ----------------
__global__ void fc_kern(const float* __restrict__ o2,
                        const float* __restrict__ fw,
                        const float* __restrict__ fb,
                        float* __restrict__ out)
{
    int gid = blockIdx.x * blockDim.x + threadIdx.x;
    if (gid >= 3072) return;
    int b = gid / 6, oo = gid - b * 6;
    const float* xr = o2 + ((size_t)b * 128 + 127) * 128;
    const float* wr = fw + oo * 128;
    float acc = fb[oo];
#pragma unroll 16
    for (int k = 0; k < 128; ++k) acc += xr[k] * wr[k];
    out[gid] = acc;
}

// ---------------- K8a: fused bf16 conversion + row norms, pair-major ----------------
// chi/clo[((l*128+s)*512 + i)*128 + h]; norms[(l*128+s)*512 + i]
__global__ __launch_bounds__(512) void prep_pairs(const float* __restrict__ o1,
                                                  const float* __restrict__ o2,
                                                  unsigned short* __restrict__ chi,
                                                  unsigned short* __restrict__ clo,
                                                  float* __restrict__ norms)
{
    const int s = blockIdx.x;          // 128
    const int l = blockIdx.y;          // 2
    const float* o = l ? o2 : o1;
    const int t = threadIdx.x;         // 512
    const int h4 = (t & 31) * 4;
    const size_t pb = ((size_t)l * 128 + s) * 512 * 128;
    float* np_ = norms + ((size_t)l * 128 + s) * 512;
#pragma unroll 1
    for (int i = t >> 5; i < 512; i += 16) {
        float4 v = *(const float4*)(o + ((size_t)i * 128 + s) * 128 + h4);
        ushort4 uh, ul;
        uh.x = f2bf(v.x); ul.x = f2bf(v.x - bf2f(uh.x));
        uh.y = f2bf(v.y); ul.y = f2bf(v.y - bf2f(uh.y));
        uh.z = f2bf(v.z); ul.z = f2bf(v.z - bf2f(uh.z));
        uh.w = f2bf(v.w); ul.w = f2bf(v.w - bf2f(uh.w));
        *(ushort4*)(chi + pb + (size_t)i * 128 + h4) = uh;
        *(ushort4*)(clo + pb + (size_t)i * 128 + h4) = ul;
        float sq = v.x * v.x + v.y * v.y + v.z * v.z + v.w * v.w;
        sq += __shfl_xor(sq, 1);
        sq += __shfl_xor(sq, 2);
        sq += __shfl_xor(sq, 4);
        sq += __shfl_xor(sq, 8);
        sq += __shfl_xor(sq, 16);
        if ((t & 31) == 0) np_[i] = sq;
    }
}

// ---------------- K8b: per-pair bandwidth ----------------
__global__ void pair_stats(const float* __restrict__ o1,
                           const float* __restrict__ o2,
                           float* __restrict__ bw)
{
    const int p = blockIdx.x;          // 256 pairs
    const int l = p >> 7, s = p & 127;
    const float* o = l ? o2 : o1;
    const int tid = threadIdx.x;       // 256
    const int h = tid & 127, half = tid >> 7;

    float acc_u = 0.f, acc_sq = 0.f;
    for (int r = 0; r < 256; ++r) {
        int i = half * 256 + r;
        float v = o[((size_t)i * 128 + s) * 128 + h];
        acc_u += v; acc_sq += v * v;
    }
    __shared__ float u2[256];
    __shared__ float red[256];
    u2[tid] = acc_u;
    red[tid] = acc_sq;
    __syncthreads();
    for (int st = 128; st > 0; st >>= 1) {
        if (tid < st) red[tid] += red[tid + st];
        __syncthreads();
    }
    float S1 = red[0];
    __syncthreads();
    float uu = 0.f;
    if (tid < 128) { float t = u2[tid] + u2[tid + 128]; uu = t * t; }
    red[tid] = uu;
    __syncthreads();
    for (int st = 128; st > 0; st >>= 1) {
        if (tid < st) red[tid] += red[tid + st];
        __syncthreads();
    }
    if (tid == 0) {
        float S2 = red[0];
        float d2s = 1024.f * S1 - 2.f * S2;
        bw[p] = d2s / (512.f * 512.f - 512.f) * 0.25f;
    }
}

// ---------------- K9: MMD via bf16 hi/lo MFMA Gram ----------------
__global__ __launch_bounds__(256) void mmd_kern(const unsigned short* __restrict__ chi,
                                                const unsigned short* __restrict__ clo,
                                                const float* __restrict__ norms,
                                                const float* __restrict__ bw,
                                                float* __restrict__ mmdv)
{
    const int lin = blockIdx.x;               // 0..2559
    const int v   = (lin & 7) * 320 + (lin >> 3);
    const int p   = v / 10;                   // pair
    const int tp  = v - p * 10;               // tile-pair
    int ti, tj;
    if (tp < 4)      { ti = 0; tj = tp; }
    else if (tp < 7) { ti = 1; tj = tp - 3; }
    else if (tp < 9) { ti = 2; tj = tp - 5; }
    else             { ti = 3; tj = 3; }
    const float sgn  = ((ti < 2) == (tj < 2)) ? 1.f : -1.f;
    const float coef = sgn * ((ti == tj) ? 1.f : 2.f);

    const int tid  = threadIdx.x;
    const int lane = tid & 63;
    const int wave = tid >> 6;                // 0..3
    const int wm = wave >> 1, wn = wave & 1;
    const int r16 = lane & 15;
    const int kq  = lane >> 4;                // 0..3

    const size_t pbase = (size_t)p * 512 * 128;
    const int arow = ti * 128 + wm * 64 + r16;
    const int brow = tj * 128 + wn * 64 + r16;

    f32x4 acc[4][4];
#pragma unroll
    for (int mf = 0; mf < 4; ++mf)
#pragma unroll
        for (int nf = 0; nf < 4; ++nf) acc[mf][nf] = (f32x4){0.f, 0.f, 0.f, 0.f};

#pragma unroll 1
    for (int kc = 0; kc < 128; kc += 32) {
        const size_t koff = (size_t)kc + 8 * kq;
        bf16x8 ah[4], al[4], bh[4], bl[4];
#pragma unroll
        for (int mf = 0; mf < 4; ++mf) {
            size_t off = pbase + (size_t)(arow + mf * 16) * 128 + koff;
            ah[mf] = *(const bf16x8*)(chi + off);
            al[mf] = *(const bf16x8*)(clo + off);
        }
#pragma unroll
        for (int nf = 0; nf < 4; ++nf) {
            size_t off = pbase + (size_t)(brow + nf * 16) * 128 + koff;
            bh[nf] = *(const bf16x8*)(chi + off);
            bl[nf] = *(const bf16x8*)(clo + off);
        }
#pragma unroll
        for (int mf = 0; mf < 4; ++mf)
#pragma unroll
            for (int nf = 0; nf < 4; ++nf) {
                acc[mf][nf] = __builtin_amdgcn_mfma_f32_16x16x32_bf16(ah[mf], bh[nf], acc[mf][nf], 0, 0, 0);
                acc[mf][nf] = __builtin_amdgcn_mfma_f32_16x16x32_bf16(ah[mf], bl[nf], acc[mf][nf], 0, 0, 0);
                acc[mf][nf] = __builtin_amdgcn_mfma_f32_16x16x32_bf16(al[mf], bh[nf], acc[mf][nf], 0, 0, 0);
            }
    }

    const float* np_ = norms + (size_t)p * 512;
    float na[4][4], nb[4];
#pragma unroll
    for (int mf = 0; mf < 4; ++mf)
#pragma unroll
        for (int r = 0; r < 4; ++r)
            na[mf][r] = np_[ti * 128 + wm * 64 + mf * 16 + (lane >> 4) * 4 + r];
#pragma unroll
    for (int nf = 0; nf < 4; ++nf)
        nb[nf] = np_[tj * 128 + wn * 64 + nf * 16 + (lane & 15)];

    const float bwv = bw[p];
    const float c4 = -1.f / (bwv * 16.f);
    float tot = 0.f;
#pragma unroll
    for (int mf = 0; mf < 4; ++mf)
#pragma unroll
        for (int nf = 0; nf < 4; ++nf)
#pragma unroll
            for (int r = 0; r < 4; ++r) {
                float d2 = na[mf][r] + nb[nf] - 2.f * acc[mf][nf][r];
                float e4 = __expf(c4 * d2);
                float e3 = e4 * e4;
                float e2 = e3 * e3;
                float e1 = e2 * e2;
                float e0 = e1 * e1;
                tot += ((e0 + e1) + (e2 + e3)) + e4;
            }
    tot *= coef;

    __shared__ float rbuf[4];
    for (int off = 32; off > 0; off >>= 1) tot += __shfl_down(tot, off);
    if ((tid & 63) == 0) rbuf[tid >> 6] = tot;
    __syncthreads();
    if (tid == 0) atomicAdd(&mmdv[p], rbuf[0] + rbuf[1] + rbuf[2] + rbuf[3]);
}

// ---------------- K10: loss = sum(wts * mmd) / 65536 ----------------
__global__ void final_loss(const float* __restrict__ wts,
                           const float* __restrict__ mmdv,
                           float* __restrict__ out)
{
    const int t = threadIdx.x;  // 256
    float v = wts[t] * mmdv[t];
    __shared__ float red[256];
    red[t] = v;
    __syncthreads();
    for (int st = 128; st > 0; st >>= 1) {
        if (t < st) red[t] += red[t + st];
        __syncthreads();
    }
    if (t == 0) out[0] = red[0] * (1.f / 65536.f);
}

// ---------------- launch ----------------
extern "C" void kernel_launch(void* const* d_in, const int* in_sizes, int n_in,
                              void* d_out, int out_size, void* d_ws, size_t ws_size,
                              hipStream_t stream)
{
    (void)in_sizes; (void)n_in; (void)out_size; (void)ws_size;
    const float* x    = (const float*)d_in[0];
    const float* wih0 = (const float*)d_in[1];
    const float* whh0 = (const float*)d_in[2];
    const float* bih0 = (const float*)d_in[3];
    const float* bhh0 = (const float*)d_in[4];
    const float* wih1 = (const float*)d_in[5];
    const float* whh1 = (const float*)d_in[6];
    const float* bih1 = (const float*)d_in[7];
    const float* bhh1 = (const float*)d_in[8];
    const float* gw0  = (const float*)d_in[9];
    const float* bg0  = (const float*)d_in[11];
    const float* bb0  = (const float*)d_in[12];
    const float* gw1  = (const float*)d_in[13];
    const float* bg1  = (const float*)d_in[15];
    const float* bb1  = (const float*)d_in[16];
    const float* fcw  = (const float*)d_in[17];
    const float* fcb  = (const float*)d_in[18];

    float* out = (float*)d_out;
    char*  ws  = (char*)d_ws;
    float* xw   = (float*)(ws + XW_OFF);
    float* o1   = (float*)(ws + O1_OFF);
    float* o2   = (float*)(ws + O2_OFF);
    float* y0   = (float*)(ws + Y0_OFF);
    float* y1   = (float*)(ws + Y1_OFF);
    float* mmdv = (float*)(ws + MMD_OFF);
    float* wts  = (float*)(ws + WTS_OFF);
    float* bwv  = (float*)(ws + BW_OFF);
    float* nrm  = (float*)(ws + NRM_OFF);
    unsigned short* chi  = (unsigned short*)(ws + CHI_OFF);
    unsigned short* clo  = (unsigned short*)(ws + CLO_OFF);
    unsigned short* abh  = (unsigned short*)(ws + ABH_OFF);   // aliases o2 (pre-gru2)
    unsigned short* abl  = (unsigned short*)(ws + ABL_OFF);
    unsigned short* whi0 = (unsigned short*)(ws + WBF_OFF);
    unsigned short* wlo0 = whi0 + 49152;
    unsigned short* whi1 = wlo0 + 49152;
    unsigned short* wlo1 = whi1 + 49152;
    unsigned short* hhi0 = wlo1 + 49152;
    unsigned short* hlo0 = hhi0 + 49152;
    unsigned short* hhi1 = hlo0 + 49152;
    unsigned short* hlo1 = hhi1 + 49152;

    hipMemsetAsync(y0, 0, (256 * 128 * 2 + 256) * sizeof(float), stream);

    cvt_w4<<<dim3(48, 4), 256, 0, stream>>>(wih0, wih1, whh0, whh1,
                                            whi0, wlo0, whi1, wlo1,
                                            hhi0, hlo0, hhi1, hlo1);

    cvt_a<<<2048, 256, 0, stream>>>(x, abh, abl);
    gemm_mfma<<<dim3(512, 3), 256, 0, stream>>>(abh, abl, whi0, wlo0, bih0, xw);
    gru_mfma<<<32, 512, 0, stream>>>(xw, hhi0, hlo0, bhh0, o1, abh, abl);  // fused cvt_a#2

    gemm_mfma<<<dim3(512, 3), 256, 0, stream>>>(abh, abl, whi1, wlo1, bih1, xw);
    gru_mfma<<<32, 512, 0, stream>>>(xw, hhi1, hlo1, bhh1, o2, (unsigned short*)nullptr,
                                     (unsigned short*)nullptr);   // overwrites abh/abl (safe)

    gate_gemm<<<dim3(4, 2, 32), 256, 0, stream>>>(o1, gw0, y0);
    gate_gemm<<<dim3(4, 2, 32), 256, 0, stream>>>(o2, gw1, y1);
    gate_reduce2<<<2, 128, 0, stream>>>(y0, y1, bg0, bb0, bg1, bb1, wts, out + 3073);

    fc_kern<<<12, 256, 0, stream>>>(o2, fcw, fcb, out);

    prep_pairs<<<dim3(128, 2), 512, 0, stream>>>(o1, o2, chi, clo, nrm);  // xw dead from here
    pair_stats<<<256, 256, 0, stream>>>(o1, o2, bwv);
    mmd_kern<<<2560, 256, 0, stream>>>(chi, clo, nrm, bwv, mmdv);
    final_loss<<<1, 256, 0, stream>>>(wts, mmdv, out + 3072);
}

// Round 19
// 759.062 us; speedup vs baseline: 1.1619x; 1.1239x over previous
//
#include <hip/hip_runtime.h>
#include <math.h>

typedef __attribute__((ext_vector_type(8))) short bf16x8;   // 8 bf16 (4 VGPRs)
typedef __attribute__((ext_vector_type(4))) float f32x4;

// ---------------- workspace layout (bytes) ----------------
constexpr size_t XW_OFF  = 0;                                   // 96 MB (gemm out; dead after 2nd gru)
constexpr size_t O1_OFF  = XW_OFF + 65536ull * 384 * 4;         // 32 MB
constexpr size_t O2_OFF  = O1_OFF + 512ull * 128 * 128 * 4;     // 32 MB (also A-bf16 staging pre-gru2)
constexpr size_t Y0_OFF  = O2_OFF + 512ull * 128 * 128 * 4;     // 128 KB
constexpr size_t Y1_OFF  = Y0_OFF + 256ull * 128 * 4;           // 128 KB
constexpr size_t MMD_OFF = Y1_OFF + 256ull * 128 * 4;           // 1 KB
constexpr size_t WTS_OFF = MMD_OFF + 256 * 4;                   // 1 KB
constexpr size_t BW_OFF  = WTS_OFF + 256 * 4;                   // 1 KB
constexpr size_t WBF_OFF = BW_OFF + 4096;                       // 8 bf16 weight slots = 786 KB
// aliases into dead regions:
constexpr size_t NRM_OFF = XW_OFF;                              // norms (after gru2)
constexpr size_t CHI_OFF = XW_OFF + (1ull << 20);               // mmd bf16 hi
constexpr size_t CLO_OFF = CHI_OFF + 36ull * 1024 * 1024;       // mmd bf16 lo
constexpr size_t ABH_OFF = O2_OFF;                              // gemm A bf16 hi (16 MB)
constexpr size_t ABL_OFF = O2_OFF + 16ull * 1024 * 1024;        // gemm A bf16 lo (16 MB)

static __device__ __forceinline__ unsigned short f2bf(float x) {
    unsigned u = __float_as_uint(x);
    unsigned r = (u + 0x7FFFu + ((u >> 16) & 1u)) >> 16;
    return (unsigned short)r;
}
static __device__ __forceinline__ float bf2f(unsigned short b) {
    return __uint_as_float((unsigned)b << 16);
}

// ---------------- K0a: 4x W f32 -> bf16 hi/lo in ONE launch ----------------
__global__ __launch_bounds__(256) void cvt_w4(const float* __restrict__ W0, const float* __restrict__ W1,
                                              const float* __restrict__ W2, const float* __restrict__ W3,
                                              unsigned short* __restrict__ H0, unsigned short* __restrict__ L0,
                                              unsigned short* __restrict__ H1, unsigned short* __restrict__ L1,
                                              unsigned short* __restrict__ H2, unsigned short* __restrict__ L2,
                                              unsigned short* __restrict__ H3, unsigned short* __restrict__ L3)
{
    const int which = blockIdx.y;
    const float* W = (which == 0) ? W0 : (which == 1) ? W1 : (which == 2) ? W2 : W3;
    unsigned short* whi = (which == 0) ? H0 : (which == 1) ? H1 : (which == 2) ? H2 : H3;
    unsigned short* wlo = (which == 0) ? L0 : (which == 1) ? L1 : (which == 2) ? L2 : L3;
    int f = blockIdx.x * 256 + threadIdx.x;
    if (f >= 12288) return;
    float4 v = ((const float4*)W)[f];
    ushort4 uh, ul;
    uh.x = f2bf(v.x); ul.x = f2bf(v.x - bf2f(uh.x));
    uh.y = f2bf(v.y); ul.y = f2bf(v.y - bf2f(uh.y));
    uh.z = f2bf(v.z); ul.z = f2bf(v.z - bf2f(uh.z));
    uh.w = f2bf(v.w); ul.w = f2bf(v.w - bf2f(uh.w));
    *(ushort4*)(whi + 4 * f) = uh;
    *(ushort4*)(wlo + 4 * f) = ul;
}

// ---------------- K0b: A f32 [M][128] -> bf16 hi/lo (only x needs this) ----------------
__global__ __launch_bounds__(256) void cvt_a(const float* __restrict__ A,
                                             unsigned short* __restrict__ ahi,
                                             unsigned short* __restrict__ alo)
{
    const int t = threadIdx.x;
#pragma unroll
    for (int it = 0; it < 4; ++it) {
        size_t f = (size_t)blockIdx.x * 1024 + it * 256 + t;
        float4 v = ((const float4*)A)[f];
        ushort4 uh, ul;
        uh.x = f2bf(v.x); ul.x = f2bf(v.x - bf2f(uh.x));
        uh.y = f2bf(v.y); ul.y = f2bf(v.y - bf2f(uh.y));
        uh.z = f2bf(v.z); ul.z = f2bf(v.z - bf2f(uh.z));
        uh.w = f2bf(v.w); ul.w = f2bf(v.w - bf2f(uh.w));
        *(ushort4*)(ahi + 4 * f) = uh;
        *(ushort4*)(alo + 4 * f) = ul;
    }
}

// ---------------- K1/K3: C[M][384] = A[M][128] @ W[384][128]^T + bias (MFMA) ----------------
__global__ __launch_bounds__(256) void gemm_mfma(const unsigned short* __restrict__ ahi,
                                                 const unsigned short* __restrict__ alo,
                                                 const unsigned short* __restrict__ whi,
                                                 const unsigned short* __restrict__ wlo,
                                                 const float* __restrict__ bias,
                                                 float* __restrict__ C)
{
    const int m0 = blockIdx.x * 128;
    const int n0 = blockIdx.y * 128;
    const int tid  = threadIdx.x;
    const int lane = tid & 63;
    const int wave = tid >> 6;
    const int wm = wave >> 1, wn = wave & 1;
    const int r16 = lane & 15;
    const int kq  = lane >> 4;

    const int arow = m0 + wm * 64 + r16;
    const int brow = n0 + wn * 64 + r16;

    f32x4 acc[4][4];
#pragma unroll
    for (int mf = 0; mf < 4; ++mf)
#pragma unroll
        for (int nf = 0; nf < 4; ++nf) acc[mf][nf] = (f32x4){0.f, 0.f, 0.f, 0.f};

#pragma unroll 1
    for (int kc = 0; kc < 128; kc += 32) {
        const int koff = kc + 8 * kq;
        bf16x8 ah[4], al[4], bh[4], bl[4];
#pragma unroll
        for (int mf = 0; mf < 4; ++mf) {
            size_t off = (size_t)(arow + mf * 16) * 128 + koff;
            ah[mf] = *(const bf16x8*)(ahi + off);
            al[mf] = *(const bf16x8*)(alo + off);
        }
#pragma unroll
        for (int nf = 0; nf < 4; ++nf) {
            size_t off = (size_t)(brow + nf * 16) * 128 + koff;
            bh[nf] = *(const bf16x8*)(whi + off);
            bl[nf] = *(const bf16x8*)(wlo + off);
        }
#pragma unroll
        for (int mf = 0; mf < 4; ++mf)
#pragma unroll
            for (int nf = 0; nf < 4; ++nf) {
                acc[mf][nf] = __builtin_amdgcn_mfma_f32_16x16x32_bf16(ah[mf], bh[nf], acc[mf][nf], 0, 0, 0);
                acc[mf][nf] = __builtin_amdgcn_mfma_f32_16x16x32_bf16(ah[mf], bl[nf], acc[mf][nf], 0, 0, 0);
                acc[mf][nf] = __builtin_amdgcn_mfma_f32_16x16x32_bf16(al[mf], bh[nf], acc[mf][nf], 0, 0, 0);
            }
    }

    float nb[4];
#pragma unroll
    for (int nf = 0; nf < 4; ++nf) nb[nf] = bias[n0 + wn * 64 + nf * 16 + r16];

#pragma unroll
    for (int mf = 0; mf < 4; ++mf)
#pragma unroll
        for (int nf = 0; nf < 4; ++nf)
#pragma unroll
            for (int r = 0; r < 4; ++r) {
                int row = m0 + wm * 64 + mf * 16 + kq * 4 + r;
                int col = n0 + wn * 64 + nf * 16 + r16;
                C[(size_t)row * 384 + col] = acc[mf][nf][r] + nb[nf];
            }
}

// ---------------- GRU step body (shared by gru_mfma and fat1) ----------------
#define GRU_BODY(STCUR, CUR, XR, XZ, XN, DO_AB)                                       \
    {                                                                                 \
        bf16x8 Bh[4], Bl[4];                                                          \
        _Pragma("unroll")                                                             \
        for (int c = 0; c < 4; ++c) {                                                 \
            int rslot = (b * 128 + 32 * c + 8 * kq) ^ ((b & 7) << 3);                 \
            Bh[c] = *(const bf16x8*)&hb[CUR][0][rslot];                               \
            Bl[c] = *(const bf16x8*)&hb[CUR][1][rslot];                               \
        }                                                                             \
        f32x4 acc[3];                                                                 \
        _Pragma("unroll")                                                             \
        for (int g = 0; g < 3; ++g) acc[g] = (f32x4){0.f, 0.f, 0.f, 0.f};             \
        _Pragma("unroll")                                                             \
        for (int c = 0; c < 4; ++c)                                                   \
            _Pragma("unroll")                                                         \
            for (int g = 0; g < 3; ++g)                                               \
                acc[g] = __builtin_amdgcn_mfma_f32_16x16x32_bf16(Ah[g][c], Bh[c], acc[g], 0, 0, 0); \
        _Pragma("unroll")                                                             \
        for (int c = 0; c < 4; ++c)                                                   \
            _Pragma("unroll")                                                         \
            for (int g = 0; g < 3; ++g)                                               \
                acc[g] = __builtin_amdgcn_mfma_f32_16x16x32_bf16(Ah[g][c], Bl[c], acc[g], 0, 0, 0); \
        _Pragma("unroll")                                                             \
        for (int c = 0; c < 4; ++c)                                                   \
            _Pragma("unroll")                                                         \
            for (int g = 0; g < 3; ++g)                                               \
                acc[g] = __builtin_amdgcn_mfma_f32_16x16x32_bf16(Al[g][c], Bh[c], acc[g], 0, 0, 0); \
        f32x4 hnew;                                                                   \
        ushort4 nhi, nlo;                                                             \
        _Pragma("unroll")                                                             \
        for (int r = 0; r < 4; ++r) {                                                 \
            float rr = 1.f / (1.f + __expf(-(XR[r] + acc[0][r] + bh[0][r])));         \
            float zz = 1.f / (1.f + __expf(-(XZ[r] + acc[1][r] + bh[1][r])));         \
            float xa = XN[r] + rr * (acc[2][r] + bh[2][r]);                           \
            float ex = __expf(-2.f * fabsf(xa));                                      \
            float th = (1.f - ex) / (1.f + ex);                                       \
            th = copysignf(th, xa);                                                   \
            hnew[r] = (1.f - zz) * th + zz * hold[r];                                 \
        }                                                                             \
        hold = hnew;                                                                  \
        nhi.x = f2bf(hnew[0]); nlo.x = f2bf(hnew[0] - bf2f(nhi.x));                   \
        nhi.y = f2bf(hnew[1]); nlo.y = f2bf(hnew[1] - bf2f(nhi.y));                   \
        nhi.z = f2bf(hnew[2]); nlo.z = f2bf(hnew[2] - bf2f(nhi.z));                   \
        nhi.w = f2bf(hnew[3]); nlo.w = f2bf(hnew[3] - bf2f(nhi.w));                   \
        *(ushort4*)&hb[(CUR) ^ 1][0][wslot] = nhi;                                    \
        *(ushort4*)&hb[(CUR) ^ 1][1][wslot] = nlo;                                    \
        *(f32x4*)(outp + ((size_t)B * 128 + (STCUR)) * 128 + u0) = hnew;              \
        if (DO_AB) {                                                                  \
            *(ushort4*)(abh + ((size_t)B * 128 + (STCUR)) * 128 + u0) = nhi;          \
            *(ushort4*)(abl + ((size_t)B * 128 + (STCUR)) * 128 + u0) = nlo;          \
        }                                                                             \
        {                                                                             \
            const int ld = ((STCUR) + 2 < 128) ? (STCUR) + 2 : 127;                   \
            XR = *(const f32x4*)(xb + ld * 384 + u0);                                 \
            XZ = *(const f32x4*)(xb + ld * 384 + 128 + u0);                           \
            XN = *(const f32x4*)(xb + ld * 384 + 256 + u0);                           \
        }                                                                             \
        asm volatile("s_waitcnt lgkmcnt(0)" ::: "memory");                            \
        __builtin_amdgcn_s_barrier();                                                 \
    }

#define GRU_PROLOGUE(BLK, WHI, WLO, BHH, XW)                                          \
    const int tid  = threadIdx.x;                                                     \
    const int w    = tid >> 6;                                                        \
    const int lane = tid & 63;                                                        \
    const int b    = lane & 15;                                                       \
    const int kq   = lane >> 4;                                                       \
    const int u0   = 16 * w + 4 * kq;                                                 \
    const int B    = (BLK) * 16 + b;                                                  \
    bf16x8 Ah[3][4], Al[3][4];                                                        \
    _Pragma("unroll")                                                                 \
    for (int g = 0; g < 3; ++g)                                                       \
        _Pragma("unroll")                                                             \
        for (int c = 0; c < 4; ++c) {                                                 \
            size_t off = (size_t)(128 * g + 16 * w + b) * 128 + 32 * c + 8 * kq;      \
            Ah[g][c] = *(const bf16x8*)((WHI) + off);                                 \
            Al[g][c] = *(const bf16x8*)((WLO) + off);                                 \
        }                                                                             \
    f32x4 bh[3];                                                                      \
    _Pragma("unroll")                                                                 \
    for (int g = 0; g < 3; ++g) bh[g] = *(const f32x4*)((BHH) + 128 * g + u0);        \
    const int wslot = (b * 128 + u0) ^ ((b & 7) << 3);                                \
    *(ushort4*)&hb[0][0][wslot] = (ushort4){0, 0, 0, 0};                              \
    *(ushort4*)&hb[0][1][wslot] = (ushort4){0, 0, 0, 0};                              \
    __syncthreads();                                                                  \
    f32x4 hold = (f32x4){0.f, 0.f, 0.f, 0.f};                                         \
    const float* xb = (XW) + (size_t)B * 128 * 384;                                   \
    f32x4 xAr = *(const f32x4*)(xb + u0);                                             \
    f32x4 xAz = *(const f32x4*)(xb + 128 + u0);                                       \
    f32x4 xAn = *(const f32x4*)(xb + 256 + u0);                                       \
    f32x4 xBr = *(const f32x4*)(xb + 384 + u0);                                       \
    f32x4 xBz = *(const f32x4*)(xb + 384 + 128 + u0);                                 \
    f32x4 xBn = *(const f32x4*)(xb + 384 + 256 + u0);

// ---------------- K2: GRU layer 1 (fused bf16 output for gemm2 A) ----------------
__global__ __launch_bounds__(512, 1) void gru_mfma(const float* __restrict__ xw,
                                                   const unsigned short* __restrict__ whi,
                                                   const unsigned short* __restrict__ wlo,
                                                   const float* __restrict__ bhh,
                                                   float* __restrict__ outp,
                                                   unsigned short* __restrict__ abh,
                                                   unsigned short* __restrict__ abl)
{
    __shared__ __align__(16) unsigned short hb[2][2][2048];
    GRU_PROLOGUE(blockIdx.x, whi, wlo, bhh, xw)
#pragma unroll 1
    for (int st = 0; st < 128; st += 2) {
        GRU_BODY(st,     0, xAr, xAz, xAn, true)
        GRU_BODY(st + 1, 1, xBr, xBz, xBn, true)
    }
}

// ---------------- 512-thread gate_gemm body (device inline) ----------------
// y[256][128] += xall @ gw^T over k-range [gz*1024, gz*1024+1024)
static __device__ __forceinline__ void gate_gemm_body(const float* __restrict__ o,
                                                      const float* __restrict__ gw,
                                                      float* __restrict__ y,
                                                      int gx, int gy, int gz,
                                                      float (*As)[36], float (*Ws)[36])
{
    const int tid = threadIdx.x;
    const int tx = tid & 15, ty = (tid >> 4) & 31;   // ty 0..31
    const int m0 = gx * 64, n0 = gy * 64;
    const int k0beg = gz * 1024;

    float acc[2][4];
#pragma unroll
    for (int i = 0; i < 2; ++i)
#pragma unroll
        for (int j = 0; j < 4; ++j) acc[i][j] = 0.f;

#pragma unroll 1
    for (int kc = k0beg; kc < k0beg + 1024; kc += 32) {
        {
            int row = tid >> 3;
            int c4  = (tid & 7) * 4;
            int kap = kc + c4;
            int s = kap >> 8, half = (kap >> 7) & 1, h = kap & 127;
            float4 va = *(const float4*)(o + ((size_t)(m0 + row + 256 * half) * 128 + s) * 128 + h);
            *(float4*)&As[row][c4] = va;
            float4 vw = *(const float4*)(gw + (size_t)(n0 + row) * 32768 + kap);
            *(float4*)&Ws[row][c4] = vw;
        }
        __syncthreads();
#pragma unroll 1
        for (int k0 = 0; k0 < 32; k0 += 4) {
            float4 a4[2], w4[4];
#pragma unroll
            for (int i = 0; i < 2; ++i) a4[i] = *(float4*)&As[ty + 32 * i][k0];
#pragma unroll
            for (int j = 0; j < 4; ++j) w4[j] = *(float4*)&Ws[tx + 16 * j][k0];
#pragma unroll
            for (int i = 0; i < 2; ++i)
#pragma unroll
                for (int j = 0; j < 4; ++j) {
                    acc[i][j] += a4[i].x * w4[j].x + a4[i].y * w4[j].y +
                                 a4[i].z * w4[j].z + a4[i].w * w4[j].w;
                }
        }
        __syncthreads();
    }
#pragma unroll
    for (int i = 0; i < 2; ++i)
#pragma unroll
        for (int j = 0; j < 4; ++j) {
            int r = m0 + ty + 32 * i, c = n0 + tx + 16 * j;
            atomicAdd(&y[r * 128 + c], acc[i][j]);
        }
}

// ---------------- 512-thread pair_stats body ----------------
static __device__ __forceinline__ void pair_stats_body(const float* __restrict__ o, int s,
                                                       float* __restrict__ bwp,
                                                       float* u2, float* red)
{
    const int tid = threadIdx.x;
    const int h = tid & 127, q = tid >> 7;   // q 0..3

    float acc_u = 0.f, acc_sq = 0.f;
    for (int r = 0; r < 128; ++r) {
        int i = q * 128 + r;
        float v = o[((size_t)i * 128 + s) * 128 + h];
        acc_u += v; acc_sq += v * v;
    }
    u2[tid] = acc_u;
    red[tid] = acc_sq;
    __syncthreads();
    for (int st = 256; st > 0; st >>= 1) {
        if (tid < st) red[tid] += red[tid + st];
        __syncthreads();
    }
    float S1 = red[0];
    __syncthreads();
    float uu = 0.f;
    if (tid < 128) {
        float t = u2[tid] + u2[tid + 128] + u2[tid + 256] + u2[tid + 384];
        uu = t * t;
    }
    red[tid] = (tid < 128) ? uu : 0.f;
    __syncthreads();
    for (int st = 64; st > 0; st >>= 1) {
        if (tid < st) red[tid] += red[tid + st];
        __syncthreads();
    }
    if (tid == 0) {
        float S2 = red[0];
        float d2s = 1024.f * S1 - 2.f * S2;
        *bwp = d2s / (512.f * 512.f - 512.f) * 0.25f;
    }
}

// ---------------- FAT1: gru2 (blocks 0..31) || gate_gemm0 (32..287) || pair_stats l0 (288..415) ----------------
__global__ __launch_bounds__(512, 1) void fat1(const float* __restrict__ xw,
                                               const unsigned short* __restrict__ whi,
                                               const unsigned short* __restrict__ wlo,
                                               const float* __restrict__ bhh,
                                               float* __restrict__ o2,
                                               const float* __restrict__ o1,
                                               const float* __restrict__ gw0,
                                               float* __restrict__ y0,
                                               float* __restrict__ bw)
{
    __shared__ __align__(16) unsigned short hb[2][2][2048];
    __shared__ __align__(16) float As[64][36];
    __shared__ __align__(16) float Ws[64][36];
    __shared__ float u2s[512];
    __shared__ float reds[512];

    const int bid = blockIdx.x;
    if (bid < 32) {
        float* outp = o2;
        const unsigned short* abh = nullptr;
        const unsigned short* abl = nullptr;
        (void)abh; (void)abl;
        GRU_PROLOGUE(bid, whi, wlo, bhh, xw)
#pragma unroll 1
        for (int st = 0; st < 128; st += 2) {
            GRU_BODY(st,     0, xAr, xAz, xAn, false)
            GRU_BODY(st + 1, 1, xBr, xBz, xBn, false)
        }
    } else if (bid < 288) {
        int g = bid - 32;                       // 0..255
        gate_gemm_body(o1, gw0, y0, g & 3, (g >> 2) & 1, g >> 3, As, Ws);
    } else {
        int s = bid - 288;                      // 0..127, layer 0
        pair_stats_body(o1, s, &bw[s], u2s, reds);
    }
}

// ---------------- FAT2: gate_gemm1 (0..255) || pair_stats l1 (256..383) || fc (384..389) ----------------
__global__ __launch_bounds__(512, 1) void fat2(const float* __restrict__ o2,
                                               const float* __restrict__ gw1,
                                               float* __restrict__ y1,
                                               float* __restrict__ bw,
                                               const float* __restrict__ fcw,
                                               const float* __restrict__ fcb,
                                               float* __restrict__ outp)
{
    __shared__ __align__(16) float As[64][36];
    __shared__ __align__(16) float Ws[64][36];
    __shared__ float u2s[512];
    __shared__ float reds[512];

    const int bid = blockIdx.x;
    if (bid < 256) {
        gate_gemm_body(o2, gw1, y1, bid & 3, (bid >> 2) & 1, bid >> 3, As, Ws);
    } else if (bid < 384) {
        int s = bid - 256;                      // layer 1 pair index = 128 + s
        pair_stats_body(o2, s, &bw[128 + s], u2s, reds);
    } else {
        int gid = (bid - 384) * 512 + threadIdx.x;
        if (gid < 3072) {
            int b = gid / 6, oo = gid - b * 6;
            const float* xr = o2 + ((size_t)b * 128 + 127) * 128;
            const float* wr = fcw + oo * 128;
            float acc = fcb[oo];
#pragma unroll 16
            for (int k = 0; k < 128; ++k) acc += xr[k] * wr[k];
            outp[gid] = acc;
        }
    }
}

// ---------------- K6: BN + sigmoid-mean + softmax, both layers in ONE launch ----------------
__global__ void gate_reduce2(const float* __restrict__ y0, const float* __restrict__ y1,
                             const float* __restrict__ g0, const float* __restrict__ b0,
                             const float* __restrict__ g1, const float* __restrict__ b1,
                             float* __restrict__ wts_ws, float* __restrict__ wts_out)
{
    const int which = blockIdx.x;
    const float* y     = which ? y1 : y0;
    const float* gamma = which ? g1 : g0;
    const float* beta  = which ? b1 : b0;
    float* ws_p  = wts_ws + which * 128;
    float* out_p = wts_out + which * 128;

    const int o = threadIdx.x;   // 128 threads
    float sum = 0.f, sumsq = 0.f;
    for (int b = 0; b < 256; ++b) {
        float v = y[b * 128 + o];
        sum += v; sumsq += v * v;
    }
    float m = sum * (1.f / 256.f);
    float var = sumsq * (1.f / 256.f) - m * m;
    float inv = rsqrtf(var + 1e-5f);
    float g = gamma[o], be = beta[o];
    float sw = 0.f;
    for (int b = 0; b < 256; ++b) {
        float v = y[b * 128 + o];
        float t = g * (v - m) * inv + be;
        sw += 1.f / (1.f + __expf(-t));
    }
    float wo = sw * (1.f / 256.f);

    __shared__ float red[128];
    red[o] = wo;
    __syncthreads();
    for (int st = 64; st > 0; st >>= 1) {
        if (o < st) red[o] = fmaxf(red[o], red[o + st]);
        __syncthreads();
    }
    float mx = red[0];
    __syncthreads();
    float e = __expf(wo - mx);
    red[o] = e;
    __syncthreads();
    for (int st = 64; st > 0; st >>= 1) {
        if (o < st) red[o] += red[o + st];
        __syncthreads();
    }
    float r = e / red[0];
    ws_p[o] = r;
    out_p[o] = r;
}

// ---------------- K8a: fused bf16 conversion + row norms, pair-major ----------------
__global__ __launch_bounds__(512) void prep_pairs(const float* __restrict__ o1,
                                                  const float* __restrict__ o2,
                                                  unsigned short* __restrict__ chi,
                                                  unsigned short* __restrict__ clo,
                                                  float* __restrict__ norms)
{
    const int s = blockIdx.x;          // 128
    const int l = blockIdx.y;          // 2
    const float* o = l ? o2 : o1;
    const int t = threadIdx.x;         // 512
    const int h4 = (t & 31) * 4;
    const size_t pb = ((size_t)l * 128 + s) * 512 * 128;
    float* np_ = norms + ((size_t)l * 128 + s) * 512;
#pragma unroll 1
    for (int i = t >> 5; i < 512; i += 16) {
        float4 v = *(const float4*)(o + ((size_t)i * 128 + s) * 128 + h4);
        ushort4 uh, ul;
        uh.x = f2bf(v.x); ul.x = f2bf(v.x - bf2f(uh.x));
        uh.y = f2bf(v.y); ul.y = f2bf(v.y - bf2f(uh.y));
        uh.z = f2bf(v.z); ul.z = f2bf(v.z - bf2f(uh.z));
        uh.w = f2bf(v.w); ul.w = f2bf(v.w - bf2f(uh.w));
        *(ushort4*)(chi + pb + (size_t)i * 128 + h4) = uh;
        *(ushort4*)(clo + pb + (size_t)i * 128 + h4) = ul;
        float sq = v.x * v.x + v.y * v.y + v.z * v.z + v.w * v.w;
        sq += __shfl_xor(sq, 1);
        sq += __shfl_xor(sq, 2);
        sq += __shfl_xor(sq, 4);
        sq += __shfl_xor(sq, 8);
        sq += __shfl_xor(sq, 16);
        if ((t & 31) == 0) np_[i] = sq;
    }
}

// ---------------- K9: MMD via bf16 hi/lo MFMA Gram ----------------
__global__ __launch_bounds__(256) void mmd_kern(const unsigned short* __restrict__ chi,
                                                const unsigned short* __restrict__ clo,
                                                const float* __restrict__ norms,
                                                const float* __restrict__ bw,
                                                float* __restrict__ mmdv)
{
    const int lin = blockIdx.x;               // 0..2559
    const int v   = (lin & 7) * 320 + (lin >> 3);
    const int p   = v / 10;                   // pair
    const int tp  = v - p * 10;               // tile-pair
    int ti, tj;
    if (tp < 4)      { ti = 0; tj = tp; }
    else if (tp < 7) { ti = 1; tj = tp - 3; }
    else if (tp < 9) { ti = 2; tj = tp - 5; }
    else             { ti = 3; tj = 3; }
    const float sgn  = ((ti < 2) == (tj < 2)) ? 1.f : -1.f;
    const float coef = sgn * ((ti == tj) ? 1.f : 2.f);

    const int tid  = threadIdx.x;
    const int lane = tid & 63;
    const int wave = tid >> 6;                // 0..3
    const int wm = wave >> 1, wn = wave & 1;
    const int r16 = lane & 15;
    const int kq  = lane >> 4;                // 0..3

    const size_t pbase = (size_t)p * 512 * 128;
    const int arow = ti * 128 + wm * 64 + r16;
    const int brow = tj * 128 + wn * 64 + r16;

    f32x4 acc[4][4];
#pragma unroll
    for (int mf = 0; mf < 4; ++mf)
#pragma unroll
        for (int nf = 0; nf < 4; ++nf) acc[mf][nf] = (f32x4){0.f, 0.f, 0.f, 0.f};

#pragma unroll 1
    for (int kc = 0; kc < 128; kc += 32) {
        const size_t koff = (size_t)kc + 8 * kq;
        bf16x8 ah[4], al[4], bh[4], bl[4];
#pragma unroll
        for (int mf = 0; mf < 4; ++mf) {
            size_t off = pbase + (size_t)(arow + mf * 16) * 128 + koff;
            ah[mf] = *(const bf16x8*)(chi + off);
            al[mf] = *(const bf16x8*)(clo + off);
        }
#pragma unroll
        for (int nf = 0; nf < 4; ++nf) {
            size_t off = pbase + (size_t)(brow + nf * 16) * 128 + koff;
            bh[nf] = *(const bf16x8*)(chi + off);
            bl[nf] = *(const bf16x8*)(clo + off);
        }
#pragma unroll
        for (int mf = 0; mf < 4; ++mf)
#pragma unroll
            for (int nf = 0; nf < 4; ++nf) {
                acc[mf][nf] = __builtin_amdgcn_mfma_f32_16x16x32_bf16(ah[mf], bh[nf], acc[mf][nf], 0, 0, 0);
                acc[mf][nf] = __builtin_amdgcn_mfma_f32_16x16x32_bf16(ah[mf], bl[nf], acc[mf][nf], 0, 0, 0);
                acc[mf][nf] = __builtin_amdgcn_mfma_f32_16x16x32_bf16(al[mf], bh[nf], acc[mf][nf], 0, 0, 0);
            }
    }

    const float* np_ = norms + (size_t)p * 512;
    float na[4][4], nb[4];
#pragma unroll
    for (int mf = 0; mf < 4; ++mf)
#pragma unroll
        for (int r = 0; r < 4; ++r)
            na[mf][r] = np_[ti * 128 + wm * 64 + mf * 16 + (lane >> 4) * 4 + r];
#pragma unroll
    for (int nf = 0; nf < 4; ++nf)
        nb[nf] = np_[tj * 128 + wn * 64 + nf * 16 + (lane & 15)];

    const float bwv = bw[p];
    const float c4 = -1.f / (bwv * 16.f);
    float tot = 0.f;
#pragma unroll
    for (int mf = 0; mf < 4; ++mf)
#pragma unroll
        for (int nf = 0; nf < 4; ++nf)
#pragma unroll
            for (int r = 0; r < 4; ++r) {
                float d2 = na[mf][r] + nb[nf] - 2.f * acc[mf][nf][r];
                float e4 = __expf(c4 * d2);
                float e3 = e4 * e4;
                float e2 = e3 * e3;
                float e1 = e2 * e2;
                float e0 = e1 * e1;
                tot += ((e0 + e1) + (e2 + e3)) + e4;
            }
    tot *= coef;

    __shared__ float rbuf[4];
    for (int off = 32; off > 0; off >>= 1) tot += __shfl_down(tot, off);
    if ((tid & 63) == 0) rbuf[tid >> 6] = tot;
    __syncthreads();
    if (tid == 0) atomicAdd(&mmdv[p], rbuf[0] + rbuf[1] + rbuf[2] + rbuf[3]);
}

// ---------------- K10: loss = sum(wts * mmd) / 65536 ----------------
__global__ void final_loss(const float* __restrict__ wts,
                           const float* __restrict__ mmdv,
                           float* __restrict__ out)
{
    const int t = threadIdx.x;  // 256
    float v = wts[t] * mmdv[t];
    __shared__ float red[256];
    red[t] = v;
    __syncthreads();
    for (int st = 128; st > 0; st >>= 1) {
        if (t < st) red[t] += red[t + st];
        __syncthreads();
    }
    if (t == 0) out[0] = red[0] * (1.f / 65536.f);
}

// ---------------- launch ----------------
extern "C" void kernel_launch(void* const* d_in, const int* in_sizes, int n_in,
                              void* d_out, int out_size, void* d_ws, size_t ws_size,
                              hipStream_t stream)
{
    (void)in_sizes; (void)n_in; (void)out_size; (void)ws_size;
    const float* x    = (const float*)d_in[0];
    const float* wih0 = (const float*)d_in[1];
    const float* whh0 = (const float*)d_in[2];
    const float* bih0 = (const float*)d_in[3];
    const float* bhh0 = (const float*)d_in[4];
    const float* wih1 = (const float*)d_in[5];
    const float* whh1 = (const float*)d_in[6];
    const float* bih1 = (const float*)d_in[7];
    const float* bhh1 = (const float*)d_in[8];
    const float* gw0  = (const float*)d_in[9];
    const float* bg0  = (const float*)d_in[11];
    const float* bb0  = (const float*)d_in[12];
    const float* gw1  = (const float*)d_in[13];
    const float* bg1  = (const float*)d_in[15];
    const float* bb1  = (const float*)d_in[16];
    const float* fcw  = (const float*)d_in[17];
    const float* fcb  = (const float*)d_in[18];

    float* out = (float*)d_out;
    char*  ws  = (char*)d_ws;
    float* xw   = (float*)(ws + XW_OFF);
    float* o1   = (float*)(ws + O1_OFF);
    float* o2   = (float*)(ws + O2_OFF);
    float* y0   = (float*)(ws + Y0_OFF);
    float* y1   = (float*)(ws + Y1_OFF);
    float* mmdv = (float*)(ws + MMD_OFF);
    float* wts  = (float*)(ws + WTS_OFF);
    float* bwv  = (float*)(ws + BW_OFF);
    float* nrm  = (float*)(ws + NRM_OFF);
    unsigned short* chi  = (unsigned short*)(ws + CHI_OFF);
    unsigned short* clo  = (unsigned short*)(ws + CLO_OFF);
    unsigned short* abh  = (unsigned short*)(ws + ABH_OFF);   // aliases o2 (pre-gru2)
    unsigned short* abl  = (unsigned short*)(ws + ABL_OFF);
    unsigned short* whi0 = (unsigned short*)(ws + WBF_OFF);
    unsigned short* wlo0 = whi0 + 49152;
    unsigned short* whi1 = wlo0 + 49152;
    unsigned short* wlo1 = whi1 + 49152;
    unsigned short* hhi0 = wlo1 + 49152;
    unsigned short* hlo0 = hhi0 + 49152;
    unsigned short* hhi1 = hlo0 + 49152;
    unsigned short* hlo1 = hhi1 + 49152;

    hipMemsetAsync(y0, 0, (256 * 128 * 2 + 256) * sizeof(float), stream);

    cvt_w4<<<dim3(48, 4), 256, 0, stream>>>(wih0, wih1, whh0, whh1,
                                            whi0, wlo0, whi1, wlo1,
                                            hhi0, hlo0, hhi1, hlo1);

    cvt_a<<<2048, 256, 0, stream>>>(x, abh, abl);
    gemm_mfma<<<dim3(512, 3), 256, 0, stream>>>(abh, abl, whi0, wlo0, bih0, xw);
    gru_mfma<<<32, 512, 0, stream>>>(xw, hhi0, hlo0, bhh0, o1, abh, abl);   // fused bf16 out

    gemm_mfma<<<dim3(512, 3), 256, 0, stream>>>(abh, abl, whi1, wlo1, bih1, xw);

    // FAT1: gru2 || gate_gemm(o1) || pair_stats(l=0)
    fat1<<<416, 512, 0, stream>>>(xw, hhi1, hlo1, bhh1, o2, o1, gw0, y0, bwv);

    // FAT2: gate_gemm(o2) || pair_stats(l=1) || fc
    fat2<<<390, 512, 0, stream>>>(o2, gw1, y1, bwv, fcw, fcb, out);

    gate_reduce2<<<2, 128, 0, stream>>>(y0, y1, bg0, bb0, bg1, bb1, wts, out + 3073);

    prep_pairs<<<dim3(128, 2), 512, 0, stream>>>(o1, o2, chi, clo, nrm);  // xw dead from here
    mmd_kern<<<2560, 256, 0, stream>>>(chi, clo, nrm, bwv, mmdv);
    final_loss<<<1, 256, 0, stream>>>(wts, mmdv, out + 3072);
}

// Round 20
// 694.385 us; speedup vs baseline: 1.2701x; 1.0931x over previous
//
#include <hip/hip_runtime.h>
#include <math.h>

typedef __attribute__((ext_vector_type(8))) short bf16x8;   // 8 bf16 (4 VGPRs)
typedef __attribute__((ext_vector_type(4))) float f32x4;

// ---------------- workspace layout (bytes) ----------------
constexpr size_t XW_OFF  = 0;                                   // 96 MB (gemm out; dead after 2nd gru)
constexpr size_t O1_OFF  = XW_OFF + 65536ull * 384 * 4;         // 32 MB
constexpr size_t O2_OFF  = O1_OFF + 512ull * 128 * 128 * 4;     // 32 MB
constexpr size_t Y0_OFF  = O2_OFF + 512ull * 128 * 128 * 4;     // 128 KB
constexpr size_t Y1_OFF  = Y0_OFF + 256ull * 128 * 4;           // 128 KB
constexpr size_t MMD_OFF = Y1_OFF + 256ull * 128 * 4;           // 1 KB
constexpr size_t WTS_OFF = MMD_OFF + 256 * 4;                   // 1 KB
constexpr size_t BW_OFF  = WTS_OFF + 256 * 4;                   // 1 KB
constexpr size_t WBF_OFF = BW_OFF + 4096;                       // bf16 weight slots
// aliases into dead xw region (valid after gru2):
constexpr size_t NRM_OFF = XW_OFF;                              // norms
constexpr size_t CHI_OFF = XW_OFF + (1ull << 20);               // mmd bf16 hi
constexpr size_t CLO_OFF = CHI_OFF + 36ull * 1024 * 1024;       // mmd bf16 lo

static __device__ __forceinline__ unsigned short f2bf(float x) {
    unsigned u = __float_as_uint(x);
    unsigned r = (u + 0x7FFFu + ((u >> 16) & 1u)) >> 16;
    return (unsigned short)r;
}
static __device__ __forceinline__ float bf2f(unsigned short b) {
    return __uint_as_float((unsigned)b << 16);
}
// 8 consecutive f32 -> bf16 hi/lo fragments (in-register split)
static __device__ __forceinline__ void cvt8(const float* __restrict__ p,
                                            bf16x8* hi, bf16x8* lo) {
    float4 v0 = *(const float4*)p;
    float4 v1 = *(const float4*)(p + 4);
    union { unsigned short us[8]; bf16x8 v; } H, L;
    float f[8] = {v0.x, v0.y, v0.z, v0.w, v1.x, v1.y, v1.z, v1.w};
#pragma unroll
    for (int i = 0; i < 8; ++i) {
        H.us[i] = f2bf(f[i]);
        L.us[i] = f2bf(f[i] - bf2f(H.us[i]));
    }
    *hi = H.v; *lo = L.v;
}

// ---------------- K0: 4x W f32 -> bf16 hi/lo in ONE launch ----------------
__global__ __launch_bounds__(256) void cvt_w4(const float* __restrict__ W0, const float* __restrict__ W1,
                                              const float* __restrict__ W2, const float* __restrict__ W3,
                                              unsigned short* __restrict__ H0, unsigned short* __restrict__ L0,
                                              unsigned short* __restrict__ H1, unsigned short* __restrict__ L1,
                                              unsigned short* __restrict__ H2, unsigned short* __restrict__ L2,
                                              unsigned short* __restrict__ H3, unsigned short* __restrict__ L3)
{
    const int which = blockIdx.y;
    const float* W = (which == 0) ? W0 : (which == 1) ? W1 : (which == 2) ? W2 : W3;
    unsigned short* whi = (which == 0) ? H0 : (which == 1) ? H1 : (which == 2) ? H2 : H3;
    unsigned short* wlo = (which == 0) ? L0 : (which == 1) ? L1 : (which == 2) ? L2 : L3;
    int f = blockIdx.x * 256 + threadIdx.x;
    if (f >= 12288) return;
    float4 v = ((const float4*)W)[f];
    ushort4 uh, ul;
    uh.x = f2bf(v.x); ul.x = f2bf(v.x - bf2f(uh.x));
    uh.y = f2bf(v.y); ul.y = f2bf(v.y - bf2f(uh.y));
    uh.z = f2bf(v.z); ul.z = f2bf(v.z - bf2f(uh.z));
    uh.w = f2bf(v.w); ul.w = f2bf(v.w - bf2f(uh.w));
    *(ushort4*)(whi + 4 * f) = uh;
    *(ushort4*)(wlo + 4 * f) = ul;
}

// ---------------- K1/K3: C[M][384] = A_f32[M][128] @ W[384][128]^T + bias ----------------
// A converted f32 -> bf16 hi/lo in-register (same bytes/elem as hi+lo; deletes cvt_a)
__global__ __launch_bounds__(256) void gemm_f32a(const float* __restrict__ A,
                                                 const unsigned short* __restrict__ whi,
                                                 const unsigned short* __restrict__ wlo,
                                                 const float* __restrict__ bias,
                                                 float* __restrict__ C)
{
    const int m0 = blockIdx.x * 128;
    const int n0 = blockIdx.y * 128;
    const int tid  = threadIdx.x;
    const int lane = tid & 63;
    const int wave = tid >> 6;
    const int wm = wave >> 1, wn = wave & 1;
    const int r16 = lane & 15;
    const int kq  = lane >> 4;

    const int arow = m0 + wm * 64 + r16;
    const int brow = n0 + wn * 64 + r16;

    f32x4 acc[4][4];
#pragma unroll
    for (int mf = 0; mf < 4; ++mf)
#pragma unroll
        for (int nf = 0; nf < 4; ++nf) acc[mf][nf] = (f32x4){0.f, 0.f, 0.f, 0.f};

#pragma unroll 1
    for (int kc = 0; kc < 128; kc += 32) {
        const int koff = kc + 8 * kq;
        bf16x8 ah[4], al[4], bh[4], bl[4];
#pragma unroll
        for (int mf = 0; mf < 4; ++mf)
            cvt8(A + (size_t)(arow + mf * 16) * 128 + koff, &ah[mf], &al[mf]);
#pragma unroll
        for (int nf = 0; nf < 4; ++nf) {
            size_t off = (size_t)(brow + nf * 16) * 128 + koff;
            bh[nf] = *(const bf16x8*)(whi + off);
            bl[nf] = *(const bf16x8*)(wlo + off);
        }
#pragma unroll
        for (int mf = 0; mf < 4; ++mf)
#pragma unroll
            for (int nf = 0; nf < 4; ++nf) {
                acc[mf][nf] = __builtin_amdgcn_mfma_f32_16x16x32_bf16(ah[mf], bh[nf], acc[mf][nf], 0, 0, 0);
                acc[mf][nf] = __builtin_amdgcn_mfma_f32_16x16x32_bf16(ah[mf], bl[nf], acc[mf][nf], 0, 0, 0);
                acc[mf][nf] = __builtin_amdgcn_mfma_f32_16x16x32_bf16(al[mf], bh[nf], acc[mf][nf], 0, 0, 0);
            }
    }

    float nb[4];
#pragma unroll
    for (int nf = 0; nf < 4; ++nf) nb[nf] = bias[n0 + wn * 64 + nf * 16 + r16];

#pragma unroll
    for (int mf = 0; mf < 4; ++mf)
#pragma unroll
        for (int nf = 0; nf < 4; ++nf)
#pragma unroll
            for (int r = 0; r < 4; ++r) {
                int row = m0 + wm * 64 + mf * 16 + kq * 4 + r;
                int col = n0 + wn * 64 + nf * 16 + r16;
                C[(size_t)row * 384 + col] = acc[mf][nf][r] + nb[nf];
            }
}

// ---------------- GRU step body (shared) ----------------
#define GRU_BODY(STCUR, CUR, XR, XZ, XN)                                              \
    {                                                                                 \
        bf16x8 Bh[4], Bl[4];                                                          \
        _Pragma("unroll")                                                             \
        for (int c = 0; c < 4; ++c) {                                                 \
            int rslot = (b * 128 + 32 * c + 8 * kq) ^ ((b & 7) << 3);                 \
            Bh[c] = *(const bf16x8*)&hb[CUR][0][rslot];                               \
            Bl[c] = *(const bf16x8*)&hb[CUR][1][rslot];                               \
        }                                                                             \
        f32x4 acc[3];                                                                 \
        _Pragma("unroll")                                                             \
        for (int g = 0; g < 3; ++g) acc[g] = (f32x4){0.f, 0.f, 0.f, 0.f};             \
        _Pragma("unroll")                                                             \
        for (int c = 0; c < 4; ++c)                                                   \
            _Pragma("unroll")                                                         \
            for (int g = 0; g < 3; ++g)                                               \
                acc[g] = __builtin_amdgcn_mfma_f32_16x16x32_bf16(Ah[g][c], Bh[c], acc[g], 0, 0, 0); \
        _Pragma("unroll")                                                             \
        for (int c = 0; c < 4; ++c)                                                   \
            _Pragma("unroll")                                                         \
            for (int g = 0; g < 3; ++g)                                               \
                acc[g] = __builtin_amdgcn_mfma_f32_16x16x32_bf16(Ah[g][c], Bl[c], acc[g], 0, 0, 0); \
        _Pragma("unroll")                                                             \
        for (int c = 0; c < 4; ++c)                                                   \
            _Pragma("unroll")                                                         \
            for (int g = 0; g < 3; ++g)                                               \
                acc[g] = __builtin_amdgcn_mfma_f32_16x16x32_bf16(Al[g][c], Bh[c], acc[g], 0, 0, 0); \
        f32x4 hnew;                                                                   \
        ushort4 nhi, nlo;                                                             \
        _Pragma("unroll")                                                             \
        for (int r = 0; r < 4; ++r) {                                                 \
            float rr = 1.f / (1.f + __expf(-(XR[r] + acc[0][r] + bh[0][r])));         \
            float zz = 1.f / (1.f + __expf(-(XZ[r] + acc[1][r] + bh[1][r])));         \
            float xa = XN[r] + rr * (acc[2][r] + bh[2][r]);                           \
            float ex = __expf(-2.f * fabsf(xa));                                      \
            float th = (1.f - ex) / (1.f + ex);                                       \
            th = copysignf(th, xa);                                                   \
            hnew[r] = (1.f - zz) * th + zz * hold[r];                                 \
        }                                                                             \
        hold = hnew;                                                                  \
        nhi.x = f2bf(hnew[0]); nlo.x = f2bf(hnew[0] - bf2f(nhi.x));                   \
        nhi.y = f2bf(hnew[1]); nlo.y = f2bf(hnew[1] - bf2f(nhi.y));                   \
        nhi.z = f2bf(hnew[2]); nlo.z = f2bf(hnew[2] - bf2f(nhi.z));                   \
        nhi.w = f2bf(hnew[3]); nlo.w = f2bf(hnew[3] - bf2f(nhi.w));                   \
        *(ushort4*)&hb[(CUR) ^ 1][0][wslot] = nhi;                                    \
        *(ushort4*)&hb[(CUR) ^ 1][1][wslot] = nlo;                                    \
        *(f32x4*)(outp + ((size_t)B * 128 + (STCUR)) * 128 + u0) = hnew;              \
        {                                                                             \
            const int ld = ((STCUR) + 2 < 128) ? (STCUR) + 2 : 127;                   \
            XR = *(const f32x4*)(xb + ld * 384 + u0);                                 \
            XZ = *(const f32x4*)(xb + ld * 384 + 128 + u0);                           \
            XN = *(const f32x4*)(xb + ld * 384 + 256 + u0);                           \
        }                                                                             \
        asm volatile("s_waitcnt lgkmcnt(0)" ::: "memory");                            \
        __builtin_amdgcn_s_barrier();                                                 \
    }

#define GRU_PROLOGUE(BLK, WHI, WLO, BHH, XW)                                          \
    const int tid  = threadIdx.x;                                                     \
    const int w    = tid >> 6;                                                        \
    const int lane = tid & 63;                                                        \
    const int b    = lane & 15;                                                       \
    const int kq   = lane >> 4;                                                       \
    const int u0   = 16 * w + 4 * kq;                                                 \
    const int B    = (BLK) * 16 + b;                                                  \
    bf16x8 Ah[3][4], Al[3][4];                                                        \
    _Pragma("unroll")                                                                 \
    for (int g = 0; g < 3; ++g)                                                       \
        _Pragma("unroll")                                                             \
        for (int c = 0; c < 4; ++c) {                                                 \
            size_t off = (size_t)(128 * g + 16 * w + b) * 128 + 32 * c + 8 * kq;      \
            Ah[g][c] = *(const bf16x8*)((WHI) + off);                                 \
            Al[g][c] = *(const bf16x8*)((WLO) + off);                                 \
        }                                                                             \
    f32x4 bh[3];                                                                      \
    _Pragma("unroll")                                                                 \
    for (int g = 0; g < 3; ++g) bh[g] = *(const f32x4*)((BHH) + 128 * g + u0);        \
    const int wslot = (b * 128 + u0) ^ ((b & 7) << 3);                                \
    *(ushort4*)&hb[0][0][wslot] = (ushort4){0, 0, 0, 0};                              \
    *(ushort4*)&hb[0][1][wslot] = (ushort4){0, 0, 0, 0};                              \
    __syncthreads();                                                                  \
    f32x4 hold = (f32x4){0.f, 0.f, 0.f, 0.f};                                         \
    const float* xb = (XW) + (size_t)B * 128 * 384;                                   \
    f32x4 xAr = *(const f32x4*)(xb + u0);                                             \
    f32x4 xAz = *(const f32x4*)(xb + 128 + u0);                                       \
    f32x4 xAn = *(const f32x4*)(xb + 256 + u0);                                       \
    f32x4 xBr = *(const f32x4*)(xb + 384 + u0);                                       \
    f32x4 xBz = *(const f32x4*)(xb + 384 + 128 + u0);                                 \
    f32x4 xBn = *(const f32x4*)(xb + 384 + 256 + u0);

// ---------------- K2: GRU layer 1 ----------------
__global__ __launch_bounds__(512, 1) void gru_mfma(const float* __restrict__ xw,
                                                   const unsigned short* __restrict__ whi,
                                                   const unsigned short* __restrict__ wlo,
                                                   const float* __restrict__ bhh,
                                                   float* __restrict__ outp)
{
    __shared__ __align__(16) unsigned short hb[2][2][2048];
    GRU_PROLOGUE(blockIdx.x, whi, wlo, bhh, xw)
#pragma unroll 1
    for (int st = 0; st < 128; st += 2) {
        GRU_BODY(st,     0, xAr, xAz, xAn)
        GRU_BODY(st + 1, 1, xBr, xBz, xBn)
    }
}

// ---------------- 512-thread gate_gemm body ----------------
static __device__ __forceinline__ void gate_gemm_body(const float* __restrict__ o,
                                                      const float* __restrict__ gw,
                                                      float* __restrict__ y,
                                                      int gx, int gy, int gz,
                                                      float (*As)[36], float (*Ws)[36])
{
    const int tid = threadIdx.x;
    const int tx = tid & 15, ty = (tid >> 4) & 31;
    const int m0 = gx * 64, n0 = gy * 64;
    const int k0beg = gz * 1024;

    float acc[2][4];
#pragma unroll
    for (int i = 0; i < 2; ++i)
#pragma unroll
        for (int j = 0; j < 4; ++j) acc[i][j] = 0.f;

#pragma unroll 1
    for (int kc = k0beg; kc < k0beg + 1024; kc += 32) {
        {
            int row = tid >> 3;
            int c4  = (tid & 7) * 4;
            int kap = kc + c4;
            int s = kap >> 8, half = (kap >> 7) & 1, h = kap & 127;
            float4 va = *(const float4*)(o + ((size_t)(m0 + row + 256 * half) * 128 + s) * 128 + h);
            *(float4*)&As[row][c4] = va;
            float4 vw = *(const float4*)(gw + (size_t)(n0 + row) * 32768 + kap);
            *(float4*)&Ws[row][c4] = vw;
        }
        __syncthreads();
#pragma unroll 1
        for (int k0 = 0; k0 < 32; k0 += 4) {
            float4 a4[2], w4[4];
#pragma unroll
            for (int i = 0; i < 2; ++i) a4[i] = *(float4*)&As[ty + 32 * i][k0];
#pragma unroll
            for (int j = 0; j < 4; ++j) w4[j] = *(float4*)&Ws[tx + 16 * j][k0];
#pragma unroll
            for (int i = 0; i < 2; ++i)
#pragma unroll
                for (int j = 0; j < 4; ++j) {
                    acc[i][j] += a4[i].x * w4[j].x + a4[i].y * w4[j].y +
                                 a4[i].z * w4[j].z + a4[i].w * w4[j].w;
                }
        }
        __syncthreads();
    }
#pragma unroll
    for (int i = 0; i < 2; ++i)
#pragma unroll
        for (int j = 0; j < 4; ++j) {
            int r = m0 + ty + 32 * i, c = n0 + tx + 16 * j;
            atomicAdd(&y[r * 128 + c], acc[i][j]);
        }
}

// ---------------- 512-thread pair_stats body ----------------
static __device__ __forceinline__ void pair_stats_body(const float* __restrict__ o, int s,
                                                       float* __restrict__ bwp,
                                                       float* u2, float* red)
{
    const int tid = threadIdx.x;
    const int h = tid & 127, q = tid >> 7;

    float acc_u = 0.f, acc_sq = 0.f;
    for (int r = 0; r < 128; ++r) {
        int i = q * 128 + r;
        float v = o[((size_t)i * 128 + s) * 128 + h];
        acc_u += v; acc_sq += v * v;
    }
    u2[tid] = acc_u;
    red[tid] = acc_sq;
    __syncthreads();
    for (int st = 256; st > 0; st >>= 1) {
        if (tid < st) red[tid] += red[tid + st];
        __syncthreads();
    }
    float S1 = red[0];
    __syncthreads();
    float uu = 0.f;
    if (tid < 128) {
        float t = u2[tid] + u2[tid + 128] + u2[tid + 256] + u2[tid + 384];
        uu = t * t;
    }
    red[tid] = (tid < 128) ? uu : 0.f;
    __syncthreads();
    for (int st = 64; st > 0; st >>= 1) {
        if (tid < st) red[tid] += red[tid + st];
        __syncthreads();
    }
    if (tid == 0) {
        float S2 = red[0];
        float d2s = 1024.f * S1 - 2.f * S2;
        *bwp = d2s / (512.f * 512.f - 512.f) * 0.25f;
    }
}

// ---------------- prep_pairs body (bf16 conv + norms, one (s,l)) ----------------
static __device__ __forceinline__ void prep_body(const float* __restrict__ o, int s, int l,
                                                 unsigned short* __restrict__ chi,
                                                 unsigned short* __restrict__ clo,
                                                 float* __restrict__ norms)
{
    const int t = threadIdx.x;         // 512
    const int h4 = (t & 31) * 4;
    const size_t pb = ((size_t)l * 128 + s) * 512 * 128;
    float* np_ = norms + ((size_t)l * 128 + s) * 512;
#pragma unroll 1
    for (int i = t >> 5; i < 512; i += 16) {
        float4 v = *(const float4*)(o + ((size_t)i * 128 + s) * 128 + h4);
        ushort4 uh, ul;
        uh.x = f2bf(v.x); ul.x = f2bf(v.x - bf2f(uh.x));
        uh.y = f2bf(v.y); ul.y = f2bf(v.y - bf2f(uh.y));
        uh.z = f2bf(v.z); ul.z = f2bf(v.z - bf2f(uh.z));
        uh.w = f2bf(v.w); ul.w = f2bf(v.w - bf2f(uh.w));
        *(ushort4*)(chi + pb + (size_t)i * 128 + h4) = uh;
        *(ushort4*)(clo + pb + (size_t)i * 128 + h4) = ul;
        float sq = v.x * v.x + v.y * v.y + v.z * v.z + v.w * v.w;
        sq += __shfl_xor(sq, 1);
        sq += __shfl_xor(sq, 2);
        sq += __shfl_xor(sq, 4);
        sq += __shfl_xor(sq, 8);
        sq += __shfl_xor(sq, 16);
        if ((t & 31) == 0) np_[i] = sq;
    }
}

// ---------------- FAT1: gru2 (0..31) || gate_gemm0 (32..287) || pair_stats l0 (288..415) ----------------
__global__ __launch_bounds__(512, 1) void fat1(const float* __restrict__ xw,
                                               const unsigned short* __restrict__ whi,
                                               const unsigned short* __restrict__ wlo,
                                               const float* __restrict__ bhh,
                                               float* __restrict__ o2,
                                               const float* __restrict__ o1,
                                               const float* __restrict__ gw0,
                                               float* __restrict__ y0,
                                               float* __restrict__ bw)
{
    __shared__ __align__(16) unsigned short hb[2][2][2048];
    __shared__ __align__(16) float As[64][36];
    __shared__ __align__(16) float Ws[64][36];
    __shared__ float u2s[512];
    __shared__ float reds[512];

    const int bid = blockIdx.x;
    if (bid < 32) {
        float* outp = o2;
        GRU_PROLOGUE(bid, whi, wlo, bhh, xw)
#pragma unroll 1
        for (int st = 0; st < 128; st += 2) {
            GRU_BODY(st,     0, xAr, xAz, xAn)
            GRU_BODY(st + 1, 1, xBr, xBz, xBn)
        }
    } else if (bid < 288) {
        int g = bid - 32;
        gate_gemm_body(o1, gw0, y0, g & 3, (g >> 2) & 1, g >> 3, As, Ws);
    } else {
        int s = bid - 288;
        pair_stats_body(o1, s, &bw[s], u2s, reds);
    }
}

// ---------------- FAT2: gate_gemm1 (0..255) || pair_stats l1 (256..383) || fc (384..389) || prep (390..645) ----------------
__global__ __launch_bounds__(512, 1) void fat2(const float* __restrict__ o2,
                                               const float* __restrict__ gw1,
                                               float* __restrict__ y1,
                                               float* __restrict__ bw,
                                               const float* __restrict__ fcw,
                                               const float* __restrict__ fcb,
                                               float* __restrict__ outp,
                                               const float* __restrict__ o1,
                                               unsigned short* __restrict__ chi,
                                               unsigned short* __restrict__ clo,
                                               float* __restrict__ norms)
{
    __shared__ __align__(16) float As[64][36];
    __shared__ __align__(16) float Ws[64][36];
    __shared__ float u2s[512];
    __shared__ float reds[512];

    const int bid = blockIdx.x;
    if (bid < 256) {
        gate_gemm_body(o2, gw1, y1, bid & 3, (bid >> 2) & 1, bid >> 3, As, Ws);
    } else if (bid < 384) {
        int s = bid - 256;
        pair_stats_body(o2, s, &bw[128 + s], u2s, reds);
    } else if (bid < 390) {
        int gid = (bid - 384) * 512 + threadIdx.x;
        if (gid < 3072) {
            int b = gid / 6, oo = gid - b * 6;
            const float* xr = o2 + ((size_t)b * 128 + 127) * 128;
            const float* wr = fcw + oo * 128;
            float acc = fcb[oo];
#pragma unroll 16
            for (int k = 0; k < 128; ++k) acc += xr[k] * wr[k];
            outp[gid] = acc;
        }
    } else {
        int idx = bid - 390;                   // 0..255
        int s = idx & 127, l = idx >> 7;
        prep_body(l ? o2 : o1, s, l, chi, clo, norms);
    }
}

// ---------------- K6: BN + sigmoid-mean + softmax, both layers ----------------
__global__ void gate_reduce2(const float* __restrict__ y0, const float* __restrict__ y1,
                             const float* __restrict__ g0, const float* __restrict__ b0,
                             const float* __restrict__ g1, const float* __restrict__ b1,
                             float* __restrict__ wts_ws, float* __restrict__ wts_out)
{
    const int which = blockIdx.x;
    const float* y     = which ? y1 : y0;
    const float* gamma = which ? g1 : g0;
    const float* beta  = which ? b1 : b0;
    float* ws_p  = wts_ws + which * 128;
    float* out_p = wts_out + which * 128;

    const int o = threadIdx.x;   // 128 threads
    float sum = 0.f, sumsq = 0.f;
    for (int b = 0; b < 256; ++b) {
        float v = y[b * 128 + o];
        sum += v; sumsq += v * v;
    }
    float m = sum * (1.f / 256.f);
    float var = sumsq * (1.f / 256.f) - m * m;
    float inv = rsqrtf(var + 1e-5f);
    float g = gamma[o], be = beta[o];
    float sw = 0.f;
    for (int b = 0; b < 256; ++b) {
        float v = y[b * 128 + o];
        float t = g * (v - m) * inv + be;
        sw += 1.f / (1.f + __expf(-t));
    }
    float wo = sw * (1.f / 256.f);

    __shared__ float red[128];
    red[o] = wo;
    __syncthreads();
    for (int st = 64; st > 0; st >>= 1) {
        if (o < st) red[o] = fmaxf(red[o], red[o + st]);
        __syncthreads();
    }
    float mx = red[0];
    __syncthreads();
    float e = __expf(wo - mx);
    red[o] = e;
    __syncthreads();
    for (int st = 64; st > 0; st >>= 1) {
        if (o < st) red[o] += red[o + st];
        __syncthreads();
    }
    float r = e / red[0];
    ws_p[o] = r;
    out_p[o] = r;
}

// ---------------- K9: MMD via bf16 hi/lo MFMA Gram ----------------
__global__ __launch_bounds__(256) void mmd_kern(const unsigned short* __restrict__ chi,
                                                const unsigned short* __restrict__ clo,
                                                const float* __restrict__ norms,
                                                const float* __restrict__ bw,
                                                float* __restrict__ mmdv)
{
    const int lin = blockIdx.x;
    const int v   = (lin & 7) * 320 + (lin >> 3);
    const int p   = v / 10;
    const int tp  = v - p * 10;
    int ti, tj;
    if (tp < 4)      { ti = 0; tj = tp; }
    else if (tp < 7) { ti = 1; tj = tp - 3; }
    else if (tp < 9) { ti = 2; tj = tp - 5; }
    else             { ti = 3; tj = 3; }
    const float sgn  = ((ti < 2) == (tj < 2)) ? 1.f : -1.f;
    const float coef = sgn * ((ti == tj) ? 1.f : 2.f);

    const int tid  = threadIdx.x;
    const int lane = tid & 63;
    const int wave = tid >> 6;
    const int wm = wave >> 1, wn = wave & 1;
    const int r16 = lane & 15;
    const int kq  = lane >> 4;

    const size_t pbase = (size_t)p * 512 * 128;
    const int arow = ti * 128 + wm * 64 + r16;
    const int brow = tj * 128 + wn * 64 + r16;

    f32x4 acc[4][4];
#pragma unroll
    for (int mf = 0; mf < 4; ++mf)
#pragma unroll
        for (int nf = 0; nf < 4; ++nf) acc[mf][nf] = (f32x4){0.f, 0.f, 0.f, 0.f};

#pragma unroll 1
    for (int kc = 0; kc < 128; kc += 32) {
        const size_t koff = (size_t)kc + 8 * kq;
        bf16x8 ah[4], al[4], bh[4], bl[4];
#pragma unroll
        for (int mf = 0; mf < 4; ++mf) {
            size_t off = pbase + (size_t)(arow + mf * 16) * 128 + koff;
            ah[mf] = *(const bf16x8*)(chi + off);
            al[mf] = *(const bf16x8*)(clo + off);
        }
#pragma unroll
        for (int nf = 0; nf < 4; ++nf) {
            size_t off = pbase + (size_t)(brow + nf * 16) * 128 + koff;
            bh[nf] = *(const bf16x8*)(chi + off);
            bl[nf] = *(const bf16x8*)(clo + off);
        }
#pragma unroll
        for (int mf = 0; mf < 4; ++mf)
#pragma unroll
            for (int nf = 0; nf < 4; ++nf) {
                acc[mf][nf] = __builtin_amdgcn_mfma_f32_16x16x32_bf16(ah[mf], bh[nf], acc[mf][nf], 0, 0, 0);
                acc[mf][nf] = __builtin_amdgcn_mfma_f32_16x16x32_bf16(ah[mf], bl[nf], acc[mf][nf], 0, 0, 0);
                acc[mf][nf] = __builtin_amdgcn_mfma_f32_16x16x32_bf16(al[mf], bh[nf], acc[mf][nf], 0, 0, 0);
            }
    }

    const float* np_ = norms + (size_t)p * 512;
    float na[4][4], nb[4];
#pragma unroll
    for (int mf = 0; mf < 4; ++mf)
#pragma unroll
        for (int r = 0; r < 4; ++r)
            na[mf][r] = np_[ti * 128 + wm * 64 + mf * 16 + (lane >> 4) * 4 + r];
#pragma unroll
    for (int nf = 0; nf < 4; ++nf)
        nb[nf] = np_[tj * 128 + wn * 64 + nf * 16 + (lane & 15)];

    const float bwv = bw[p];
    const float c4 = -1.f / (bwv * 16.f);
    float tot = 0.f;
#pragma unroll
    for (int mf = 0; mf < 4; ++mf)
#pragma unroll
        for (int nf = 0; nf < 4; ++nf)
#pragma unroll
            for (int r = 0; r < 4; ++r) {
                float d2 = na[mf][r] + nb[nf] - 2.f * acc[mf][nf][r];
                float e4 = __expf(c4 * d2);
                float e3 = e4 * e4;
                float e2 = e3 * e3;
                float e1 = e2 * e2;
                float e0 = e1 * e1;
                tot += ((e0 + e1) + (e2 + e3)) + e4;
            }
    tot *= coef;

    __shared__ float rbuf[4];
    for (int off = 32; off > 0; off >>= 1) tot += __shfl_down(tot, off);
    if ((tid & 63) == 0) rbuf[tid >> 6] = tot;
    __syncthreads();
    if (tid == 0) atomicAdd(&mmdv[p], rbuf[0] + rbuf[1] + rbuf[2] + rbuf[3]);
}

// ---------------- K10: loss = sum(wts * mmd) / 65536 ----------------
__global__ void final_loss(const float* __restrict__ wts,
                           const float* __restrict__ mmdv,
                           float* __restrict__ out)
{
    const int t = threadIdx.x;  // 256
    float v = wts[t] * mmdv[t];
    __shared__ float red[256];
    red[t] = v;
    __syncthreads();
    for (int st = 128; st > 0; st >>= 1) {
        if (t < st) red[t] += red[t + st];
        __syncthreads();
    }
    if (t == 0) out[0] = red[0] * (1.f / 65536.f);
}

// ---------------- launch ----------------
extern "C" void kernel_launch(void* const* d_in, const int* in_sizes, int n_in,
                              void* d_out, int out_size, void* d_ws, size_t ws_size,
                              hipStream_t stream)
{
    (void)in_sizes; (void)n_in; (void)out_size; (void)ws_size;
    const float* x    = (const float*)d_in[0];
    const float* wih0 = (const float*)d_in[1];
    const float* whh0 = (const float*)d_in[2];
    const float* bih0 = (const float*)d_in[3];
    const float* bhh0 = (const float*)d_in[4];
    const float* wih1 = (const float*)d_in[5];
    const float* whh1 = (const float*)d_in[6];
    const float* bih1 = (const float*)d_in[7];
    const float* bhh1 = (const float*)d_in[8];
    const float* gw0  = (const float*)d_in[9];
    const float* bg0  = (const float*)d_in[11];
    const float* bb0  = (const float*)d_in[12];
    const float* gw1  = (const float*)d_in[13];
    const float* bg1  = (const float*)d_in[15];
    const float* bb1  = (const float*)d_in[16];
    const float* fcw  = (const float*)d_in[17];
    const float* fcb  = (const float*)d_in[18];

    float* out = (float*)d_out;
    char*  ws  = (char*)d_ws;
    float* xw   = (float*)(ws + XW_OFF);
    float* o1   = (float*)(ws + O1_OFF);
    float* o2   = (float*)(ws + O2_OFF);
    float* y0   = (float*)(ws + Y0_OFF);
    float* y1   = (float*)(ws + Y1_OFF);
    float* mmdv = (float*)(ws + MMD_OFF);
    float* wts  = (float*)(ws + WTS_OFF);
    float* bwv  = (float*)(ws + BW_OFF);
    float* nrm  = (float*)(ws + NRM_OFF);
    unsigned short* chi  = (unsigned short*)(ws + CHI_OFF);
    unsigned short* clo  = (unsigned short*)(ws + CLO_OFF);
    unsigned short* whi0 = (unsigned short*)(ws + WBF_OFF);
    unsigned short* wlo0 = whi0 + 49152;
    unsigned short* whi1 = wlo0 + 49152;
    unsigned short* wlo1 = whi1 + 49152;
    unsigned short* hhi0 = wlo1 + 49152;
    unsigned short* hlo0 = hhi0 + 49152;
    unsigned short* hhi1 = hlo0 + 49152;
    unsigned short* hlo1 = hhi1 + 49152;

    hipMemsetAsync(y0, 0, (256 * 128 * 2 + 256) * sizeof(float), stream);

    cvt_w4<<<dim3(48, 4), 256, 0, stream>>>(wih0, wih1, whh0, whh1,
                                            whi0, wlo0, whi1, wlo1,
                                            hhi0, hlo0, hhi1, hlo1);

    gemm_f32a<<<dim3(512, 3), 256, 0, stream>>>(x, whi0, wlo0, bih0, xw);     // no cvt_a
    gru_mfma<<<32, 512, 0, stream>>>(xw, hhi0, hlo0, bhh0, o1);               // no fused stores

    gemm_f32a<<<dim3(512, 3), 256, 0, stream>>>(o1, whi1, wlo1, bih1, xw);

    // FAT1: gru2 || gate_gemm(o1) || pair_stats(l=0)
    fat1<<<416, 512, 0, stream>>>(xw, hhi1, hlo1, bhh1, o2, o1, gw0, y0, bwv);

    // FAT2: gate_gemm(o2) || pair_stats(l=1) || fc || prep_pairs
    fat2<<<646, 512, 0, stream>>>(o2, gw1, y1, bwv, fcw, fcb, out, o1, chi, clo, nrm);

    gate_reduce2<<<2, 128, 0, stream>>>(y0, y1, bg0, bb0, bg1, bb1, wts, out + 3073);

    mmd_kern<<<2560, 256, 0, stream>>>(chi, clo, nrm, bwv, mmdv);
    final_loss<<<1, 256, 0, stream>>>(wts, mmdv, out + 3072);
}